// Round 9
// baseline (550.299 us; speedup 1.0000x reference)
//
#include <hip/hip_runtime.h>
#include <hip/hip_fp16.h>
#include <math.h>

// GAT 2-layer + BN + classifier, MI355X.
// R19 = R18 resubmitted verbatim (R18 bench was an infra failure: container
// died twice, no data). BN-stats fused into k_agg epilogue (slotted atomics,
// 8 slots by blockIdx&7), removing both k_bnstats launches and their 25.6MB
// re-reads. Consumers (gemm2 fuse, k_cls) sum the 8 slots.
// k_agg gather = R11 exact (compulsory-fabric-traffic floor ~67us).
// 7 launches: setup, pre(gemm1||binA), fillB, agg1, gemm2, agg2, cls.

#define CDIM 128
#define NCLS_ 40
#define NEG_SLOPE_ 0.2f
#define BN_EPS_ 1e-5f
#define BRNG 256        // nodes per bucket (power of 2)
#define BCAP 6144       // max edges per bucket (mean 4096)
#define EPB 16          // edges per thread in binA phase (4096 per block)

using short8  = __attribute__((ext_vector_type(8))) short;
using short4v = __attribute__((ext_vector_type(4))) short;
using f32x4   = __attribute__((ext_vector_type(4))) float;

static __device__ __forceinline__ float lrelu(float a) {
    return a > 0.f ? a : NEG_SLOPE_ * a;
}
// fp32 -> bf16 round-to-nearest-even
static __device__ __forceinline__ short f2bf(float f) {
    unsigned u = __float_as_uint(f);
    u += 0x7fffu + ((u >> 16) & 1u);
    return (short)(u >> 16);
}
static __device__ __forceinline__ float bf_lo(unsigned u) { return __uint_as_float(u << 16); }
static __device__ __forceinline__ float bf_hi(unsigned u) { return __uint_as_float(u & 0xffff0000u); }
static __device__ __forceinline__ __half2 u2h2(unsigned u) { return __builtin_bit_cast(__half2, u); }
static __device__ __forceinline__ unsigned h22u(__half2 h) { return __builtin_bit_cast(unsigned, h); }

// sum 8 BN slots and build scale/shift for 4 channels (cb..cb+3)
static __device__ __forceinline__ void bn_coeffs(
    const float* __restrict__ bnsum, int cb, float invn,
    const float* __restrict__ gamma, const float* __restrict__ beta,
    float4* sc4, float4* sh4)
{
    float s0x = 0.f, s0y = 0.f, s0z = 0.f, s0w = 0.f;
    float s1x = 0.f, s1y = 0.f, s1z = 0.f, s1w = 0.f;
    #pragma unroll
    for (int sl = 0; sl < 8; sl++) {
        const float* bp = bnsum + sl * 256;
        float4 a = *(const float4*)(bp + cb);
        float4 b = *(const float4*)(bp + 128 + cb);
        s0x += a.x; s0y += a.y; s0z += a.z; s0w += a.w;
        s1x += b.x; s1y += b.y; s1z += b.z; s1w += b.w;
    }
    float4 gm = *(const float4*)(gamma + cb);
    float4 bt = *(const float4*)(beta + cb);
    float mean, var;
    mean = s0x * invn; var = fmaxf(s1x * invn - mean * mean, 0.f);
    sc4->x = gm.x * rsqrtf(var + BN_EPS_); sh4->x = bt.x - mean * sc4->x;
    mean = s0y * invn; var = fmaxf(s1y * invn - mean * mean, 0.f);
    sc4->y = gm.y * rsqrtf(var + BN_EPS_); sh4->y = bt.y - mean * sc4->y;
    mean = s0z * invn; var = fmaxf(s1z * invn - mean * mean, 0.f);
    sc4->z = gm.z * rsqrtf(var + BN_EPS_); sh4->z = bt.z - mean * sc4->z;
    mean = s0w * invn; var = fmaxf(s1w * invn - mean * mean, 0.f);
    sc4->w = gm.w * rsqrtf(var + BN_EPS_); sh4->w = bt.w - mean * sc4->w;
}

// ---------------- setup: cursors=0, bn sums=0, offs[n], W->bf16^T, ws/wd ---
__global__ void k_setup(int* bcur, float* bnsum, int NB, int n, int E, int* offs,
                        const float* __restrict__ W1, const float* __restrict__ W2,
                        const float* __restrict__ Wc,
                        const float* __restrict__ as1, const float* __restrict__ ad1,
                        const float* __restrict__ as2, const float* __restrict__ ad2,
                        short* __restrict__ Wt1, short* __restrict__ Wt2,
                        short* __restrict__ Wtc,
                        short* __restrict__ wsd1, short* __restrict__ wsd2) {
    int i = blockIdx.x * blockDim.x + threadIdx.x;
    if (i < NB) bcur[i] = 0;
    if (i < 4096) bnsum[i] = 0.f;   // 2 layers x 8 slots x 256
    if (i == 0) offs[n] = E + n;
    if (i < 128 * 128) {
        int k = i >> 7, nn = i & 127;
        Wt1[nn * 128 + k] = f2bf(W1[i]);
        Wt2[nn * 128 + k] = f2bf(W2[i]);
    }
    if (i < 48 * 128) {             // padded bf16 Wc^T [48][128]
        int nn = i >> 7, k = i & 127;
        Wtc[i] = (nn < NCLS_) ? f2bf(Wc[k * NCLS_ + nn]) : (short)0;
    }
    if (i < 128) {                  // ws = W @ a_s, wd = W @ a_d (both layers)
        float s1 = 0.f, d1 = 0.f, s2 = 0.f, d2 = 0.f;
        for (int nn2 = 0; nn2 < 128; nn2++) {
            float w1v = W1[i * 128 + nn2], w2v = W2[i * 128 + nn2];
            s1 = fmaf(w1v, as1[nn2], s1); d1 = fmaf(w1v, ad1[nn2], d1);
            s2 = fmaf(w2v, as2[nn2], s2); d2 = fmaf(w2v, ad2[nn2], d2);
        }
        wsd1[i] = f2bf(s1); wsd1[128 + i] = f2bf(d1);
        wsd2[i] = f2bf(s2); wsd2[128 + i] = f2bf(d2);
    }
}

// ---------------- FAT: layer-1 GEMM (blocks<gemmN) || edge binning ---------
__global__ __launch_bounds__(256) void k_pre(
    const float* __restrict__ Xf, const short* __restrict__ Wt,
    const short* __restrict__ wsd, short* __restrict__ Hh,
    float* __restrict__ alpha_s, float* __restrict__ alpha_d, int n, int gemmN,
    const int* __restrict__ src, const int* __restrict__ dst, int E,
    int* __restrict__ bcur, uint2* __restrict__ bucket, int NB)
{
    __shared__ union {
        struct { short As[64 * 128]; short Bs[128 * 128]; short wl[256]; } g;
        struct { int hist[400]; int base[400]; } b;
    } sm;
    int t = threadIdx.x;

    if (blockIdx.x >= gemmN) {
        // ---------------- binA body ----------------
        int bid = blockIdx.x - gemmN;
        int* hist = sm.b.hist;
        int* base = sm.b.base;
        long e0 = (long)bid * (256 * EPB) + t;

        for (int i = t; i < NB; i += 256) hist[i] = 0;
        __syncthreads();

        int sv[EPB], dv[EPB];
        #pragma unroll
        for (int i = 0; i < EPB; i++) {
            long e = e0 + (long)i * 256;
            if (e < E) {
                sv[i] = src[e]; dv[i] = dst[e];
                atomicAdd(&hist[dv[i] >> 8], 1);
            } else dv[i] = -1;
        }
        __syncthreads();

        for (int i = t; i < NB; i += 256) {
            int h = hist[i];
            base[i] = (h > 0) ? atomicAdd(&bcur[i], h) : 0;
        }
        __syncthreads();
        for (int i = t; i < NB; i += 256) hist[i] = 0;   // reuse as cursor
        __syncthreads();

        #pragma unroll
        for (int i = 0; i < EPB; i++) {
            if (dv[i] >= 0) {
                int b = dv[i] >> 8;
                int pos = base[b] + atomicAdd(&hist[b], 1);
                if (pos < BCAP)
                    bucket[(size_t)b * BCAP + pos] =
                        make_uint2((unsigned)sv[i], (unsigned)dv[i]);
            }
        }
        return;
    }

    // ---------------- layer-1 GEMM body (fp32 input, no BN fuse) ----------
    short* As = sm.g.As;
    short* Bs = sm.g.Bs;
    short* wl = sm.g.wl;
    int row0 = blockIdx.x * 64;

    for (int j = 0; j < 8; j++) {
        int idx = j * 256 + t;
        int nn = idx >> 4, cc = idx & 15;
        *(short8*)(Bs + nn * 128 + cc * 8) = *(const short8*)(Wt + nn * 128 + cc * 8);
    }
    if (t < 256) wl[t] = wsd[t];
    for (int j = 0; j < 8; j++) {
        int idx = j * 256 + t;
        int r = idx >> 5, k4 = idx & 31;
        int gr = row0 + r;
        float4 xv = make_float4(0.f, 0.f, 0.f, 0.f);
        if (gr < n) xv = *(const float4*)(Xf + (size_t)gr * CDIM + k4 * 4);
        short4v o;
        o.x = f2bf(xv.x); o.y = f2bf(xv.y); o.z = f2bf(xv.z); o.w = f2bf(xv.w);
        *(short4v*)(As + r * 128 + k4 * 4) = o;
    }
    __syncthreads();

    int w = t >> 6, lane = t & 63, q = lane >> 4, c = lane & 15;
    f32x4 zero = {0.f, 0.f, 0.f, 0.f};
    f32x4 acc[4][2];
    f32x4 acc_a = zero;               // alpha: col0=alpha_s, col1=alpha_d
    for (int i = 0; i < 4; i++) { acc[i][0] = zero; acc[i][1] = zero; }

    for (int ks = 0; ks < 4; ks++) {
        int k0 = ks * 32 + q * 8;
        short8 a0 = *(short8*)(As + (c) * 128 + k0);
        short8 a1 = *(short8*)(As + (16 + c) * 128 + k0);
        short8 a2 = *(short8*)(As + (32 + c) * 128 + k0);
        short8 a3 = *(short8*)(As + (48 + c) * 128 + k0);
        short8 b0 = *(short8*)(Bs + (w * 32 + c) * 128 + k0);
        short8 b1 = *(short8*)(Bs + (w * 32 + 16 + c) * 128 + k0);
        acc[0][0] = __builtin_amdgcn_mfma_f32_16x16x32_bf16(a0, b0, acc[0][0], 0, 0, 0);
        acc[1][0] = __builtin_amdgcn_mfma_f32_16x16x32_bf16(a1, b0, acc[1][0], 0, 0, 0);
        acc[2][0] = __builtin_amdgcn_mfma_f32_16x16x32_bf16(a2, b0, acc[2][0], 0, 0, 0);
        acc[3][0] = __builtin_amdgcn_mfma_f32_16x16x32_bf16(a3, b0, acc[3][0], 0, 0, 0);
        acc[0][1] = __builtin_amdgcn_mfma_f32_16x16x32_bf16(a0, b1, acc[0][1], 0, 0, 0);
        acc[1][1] = __builtin_amdgcn_mfma_f32_16x16x32_bf16(a1, b1, acc[1][1], 0, 0, 0);
        acc[2][1] = __builtin_amdgcn_mfma_f32_16x16x32_bf16(a2, b1, acc[2][1], 0, 0, 0);
        acc[3][1] = __builtin_amdgcn_mfma_f32_16x16x32_bf16(a3, b1, acc[3][1], 0, 0, 0);

        short8 ba;
        #pragma unroll
        for (int jj = 0; jj < 8; jj++) {
            short vs = wl[k0 + jj], vd = wl[128 + k0 + jj];
            ba[jj] = (c == 0) ? vs : ((c == 1) ? vd : (short)0);
        }
        short8 aw = (w == 0) ? a0 : ((w == 1) ? a1 : ((w == 2) ? a2 : a3));
        acc_a = __builtin_amdgcn_mfma_f32_16x16x32_bf16(aw, ba, acc_a, 0, 0, 0);
    }

    __syncthreads();                  // all As reads done before reuse

    short* Hs = As;
    #pragma unroll
    for (int mt = 0; mt < 4; mt++)
        #pragma unroll
        for (int nt = 0; nt < 2; nt++)
            #pragma unroll
            for (int r = 0; r < 4; r++)
                Hs[(mt * 16 + q * 4 + r) * 128 + w * 32 + nt * 16 + c] =
                    (short)__half_as_ushort(__float2half_rn(acc[mt][nt][r]));

    if (c < 2) {
        #pragma unroll
        for (int r = 0; r < 4; r++) {
            int row = row0 + w * 16 + q * 4 + r;
            if (row < n) {
                if (c == 0) alpha_s[row] = acc_a[r];
                else        alpha_d[row] = acc_a[r];
            }
        }
    }
    __syncthreads();

    for (int j = 0; j < 4; j++) {
        int idx = j * 256 + t;
        int r = idx >> 4, cc = idx & 15;
        int gr = row0 + r;
        if (gr < n)
            *(short8*)(Hh + (size_t)gr * 128 + cc * 8) = *(short8*)(Hs + r * 128 + cc * 8);
    }
}

// ---------------- per-bucket CSR build in LDS ------------------------------
__global__ __launch_bounds__(256) void k_fillB(
    const uint2* __restrict__ bucket, const int* __restrict__ bcur,
    int n, int NB, int* __restrict__ offs, int* __restrict__ csr)
{
    __shared__ int hist[256];
    __shared__ int scanb[256];
    __shared__ int cur[256];
    __shared__ int buf[BCAP + BRNG];
    int b = blockIdx.x, t = threadIdx.x;
    int node0 = b << 8;
    int nodesIn = min(BRNG, n - node0);
    int cnt = min(bcur[b], BCAP);
    const uint2* mybkt = bucket + (size_t)b * BCAP;

    int part = 0;
    for (int j = t; j < b; j += 256) part += min(bcur[j], BCAP);
    scanb[t] = part; __syncthreads();
    for (int s2 = 128; s2 > 0; s2 >>= 1) {
        if (t < s2) scanb[t] += scanb[t + s2];
        __syncthreads();
    }
    int base = scanb[0] + node0;
    __syncthreads();

    hist[t] = 0; __syncthreads();
    for (int e2 = t; e2 < cnt; e2 += 256)
        atomicAdd(&hist[mybkt[e2].y & 255], 1);
    __syncthreads();

    int v = hist[t] + ((t < nodesIn) ? 1 : 0);
    scanb[t] = v; __syncthreads();
    for (int d = 1; d < 256; d <<= 1) {
        int x2 = (t >= d) ? scanb[t - d] : 0;
        __syncthreads();
        scanb[t] += x2;
        __syncthreads();
    }
    int lo = scanb[t] - v;
    if (t < nodesIn) {
        offs[node0 + t] = base + lo;
        buf[lo] = node0 + t;          // self-loop occupies slot 0
        cur[t] = lo + 1;
    }
    __syncthreads();

    for (int e2 = t; e2 < cnt; e2 += 256) {
        uint2 ed = mybkt[e2];
        int pos = atomicAdd(&cur[ed.y & 255], 1);
        buf[pos] = (int)ed.x;
    }
    __syncthreads();

    int tot = cnt + nodesIn;
    for (int j2 = t; j2 < tot; j2 += 256) csr[base + j2] = buf[j2];
}

// ---------------- MFMA GEMM (layer 2): Hh = act(bn(G)) @ W, alpha fused ----
__global__ __launch_bounds__(256) void k_gemm_mfma(
    const unsigned* __restrict__ Xb, const short* __restrict__ Wt,
    const short* __restrict__ wsd,
    const float* __restrict__ bnsum, const float* __restrict__ gamma,
    const float* __restrict__ beta, float invn,
    short* __restrict__ Hh, float* __restrict__ alpha_s, float* __restrict__ alpha_d,
    int n)
{
    __shared__ short As[64 * 128];    // 16.4 KB (reused as H transpose buffer)
    __shared__ short Bs[128 * 128];   // 32.8 KB
    __shared__ short wl[256];         // ws (0..127), wd (128..255) bf16
    int t = threadIdx.x;
    int row0 = blockIdx.x * 64;

    for (int j = 0; j < 8; j++) {
        int idx = j * 256 + t;
        int nn = idx >> 4, cc = idx & 15;
        *(short8*)(Bs + nn * 128 + cc * 8) = *(const short8*)(Wt + nn * 128 + cc * 8);
    }
    if (t < 256) wl[t] = wsd[t];
    float4 sc4, sh4;
    bn_coeffs(bnsum, (t & 31) * 4, invn, gamma, beta, &sc4, &sh4);
    for (int j = 0; j < 8; j++) {
        int idx = j * 256 + t;
        int r = idx >> 5, k4 = idx & 31;
        int gr = row0 + r;
        float4 xv = make_float4(0.f, 0.f, 0.f, 0.f);
        if (gr < n) {
            uint2 u = *(const uint2*)(Xb + (size_t)gr * 64 + k4 * 2);
            xv.x = bf_lo(u.x); xv.y = bf_hi(u.x);
            xv.z = bf_lo(u.y); xv.w = bf_hi(u.y);
        }
        xv.x = fmaxf(fmaf(xv.x, sc4.x, sh4.x), 0.f);
        xv.y = fmaxf(fmaf(xv.y, sc4.y, sh4.y), 0.f);
        xv.z = fmaxf(fmaf(xv.z, sc4.z, sh4.z), 0.f);
        xv.w = fmaxf(fmaf(xv.w, sc4.w, sh4.w), 0.f);
        short4v o;
        o.x = f2bf(xv.x); o.y = f2bf(xv.y); o.z = f2bf(xv.z); o.w = f2bf(xv.w);
        *(short4v*)(As + r * 128 + k4 * 4) = o;
    }
    __syncthreads();

    int w = t >> 6, lane = t & 63, q = lane >> 4, c = lane & 15;
    f32x4 zero = {0.f, 0.f, 0.f, 0.f};
    f32x4 acc[4][2];
    f32x4 acc_a = zero;
    for (int i = 0; i < 4; i++) { acc[i][0] = zero; acc[i][1] = zero; }

    for (int ks = 0; ks < 4; ks++) {
        int k0 = ks * 32 + q * 8;
        short8 a0 = *(short8*)(As + (c) * 128 + k0);
        short8 a1 = *(short8*)(As + (16 + c) * 128 + k0);
        short8 a2 = *(short8*)(As + (32 + c) * 128 + k0);
        short8 a3 = *(short8*)(As + (48 + c) * 128 + k0);
        short8 b0 = *(short8*)(Bs + (w * 32 + c) * 128 + k0);
        short8 b1 = *(short8*)(Bs + (w * 32 + 16 + c) * 128 + k0);
        acc[0][0] = __builtin_amdgcn_mfma_f32_16x16x32_bf16(a0, b0, acc[0][0], 0, 0, 0);
        acc[1][0] = __builtin_amdgcn_mfma_f32_16x16x32_bf16(a1, b0, acc[1][0], 0, 0, 0);
        acc[2][0] = __builtin_amdgcn_mfma_f32_16x16x32_bf16(a2, b0, acc[2][0], 0, 0, 0);
        acc[3][0] = __builtin_amdgcn_mfma_f32_16x16x32_bf16(a3, b0, acc[3][0], 0, 0, 0);
        acc[0][1] = __builtin_amdgcn_mfma_f32_16x16x32_bf16(a0, b1, acc[0][1], 0, 0, 0);
        acc[1][1] = __builtin_amdgcn_mfma_f32_16x16x32_bf16(a1, b1, acc[1][1], 0, 0, 0);
        acc[2][1] = __builtin_amdgcn_mfma_f32_16x16x32_bf16(a2, b1, acc[2][1], 0, 0, 0);
        acc[3][1] = __builtin_amdgcn_mfma_f32_16x16x32_bf16(a3, b1, acc[3][1], 0, 0, 0);

        short8 ba;
        #pragma unroll
        for (int jj = 0; jj < 8; jj++) {
            short vs = wl[k0 + jj], vd = wl[128 + k0 + jj];
            ba[jj] = (c == 0) ? vs : ((c == 1) ? vd : (short)0);
        }
        short8 aw = (w == 0) ? a0 : ((w == 1) ? a1 : ((w == 2) ? a2 : a3));
        acc_a = __builtin_amdgcn_mfma_f32_16x16x32_bf16(aw, ba, acc_a, 0, 0, 0);
    }

    __syncthreads();

    short* Hs = As;
    #pragma unroll
    for (int mt = 0; mt < 4; mt++)
        #pragma unroll
        for (int nt = 0; nt < 2; nt++)
            #pragma unroll
            for (int r = 0; r < 4; r++)
                Hs[(mt * 16 + q * 4 + r) * 128 + w * 32 + nt * 16 + c] =
                    (short)__half_as_ushort(__float2half_rn(acc[mt][nt][r]));

    if (c < 2) {
        #pragma unroll
        for (int r = 0; r < 4; r++) {
            int row = row0 + w * 16 + q * 4 + r;
            if (row < n) {
                if (c == 0) alpha_s[row] = acc_a[r];
                else        alpha_d[row] = acc_a[r];
            }
        }
    }
    __syncthreads();

    for (int j = 0; j < 4; j++) {
        int idx = j * 256 + t;
        int r = idx >> 4, cc = idx & 15;
        int gr = row0 + r;
        if (gr < n)
            *(short8*)(Hh + (size_t)gr * 128 + cc * 8) = *(short8*)(Hs + r * 128 + cc * 8);
    }
}

// ---------------- ONE-PASS softmax + aggregation + fused BN stats ----------
// Gather loop = R11 exact. Epilogue: per-block LDS reduce of the 4 nodes'
// fp32 outputs, then slotted atomicAdd (slot = blockIdx&7) into bnout
// [slot*256 + ch] (sums) / [slot*256 + 128 + ch] (sumsq).
__global__ __launch_bounds__(256) void k_agg(
    const unsigned* __restrict__ Hh, const int* __restrict__ offs,
    const int* __restrict__ csr, const float* __restrict__ alpha_s,
    const float* __restrict__ alpha_d, const float* __restrict__ bias,
    unsigned* __restrict__ Ob, float* __restrict__ bnout, int n)
{
    __shared__ float red[4][64][4];
    int i = blockIdx.x * 4 + (threadIdx.x >> 6);
    int lane = threadIdx.x & 63;
    int wid = threadIdx.x >> 6;
    bool valid = (i < n);
    float rx = 0.f, ry = 0.f;

    if (valid) {
        int o0 = offs[i], o1 = offs[i + 1];
        float adi = alpha_d[i];

        float m = -1e30f;
        float se = 0.f;
        __half2 acc2 = __floats2half2_rn(0.f, 0.f);

        for (int c0 = o0; c0 < o1; c0 += 64) {
            int j = c0 + lane;
            int cnt = min(64, o1 - c0);
            int sj = (j < o1) ? csr[j] : 0;   // invalid lanes -> row 0 (w=0)

            // ---- issue up to 24 H-row gathers (independent of weights) ----
            unsigned ua[8], ub[8], uc[8];
            #pragma unroll
            for (int q = 0; q < 8; q++) {
                int s = __builtin_amdgcn_readlane(sj, q);
                ua[q] = Hh[(size_t)(unsigned)s * 64 + lane];
            }
            if (cnt > 8) {
                #pragma unroll
                for (int q = 0; q < 8; q++) {
                    int s = __builtin_amdgcn_readlane(sj, 8 + q);
                    ub[q] = Hh[(size_t)(unsigned)s * 64 + lane];
                }
            }
            if (cnt > 16) {
                #pragma unroll
                for (int q = 0; q < 8; q++) {
                    int s = __builtin_amdgcn_readlane(sj, 16 + q);
                    uc[q] = Hh[(size_t)(unsigned)s * 64 + lane];
                }
            }

            // ---- softmax weights (overlaps the in-flight gathers) ----
            float a = (j < o1) ? lrelu(alpha_s[sj] + adi) : -1e30f;
            float cm = a;
            #pragma unroll
            for (int o = 32; o > 0; o >>= 1) cm = fmaxf(cm, __shfl_xor(cm, o));
            if (cm > m) {
                float r = __expf(m - cm);
                se *= r;
                acc2 = __hmul2(acc2, __float2half2_rn(r));
                m = cm;
            }
            float wl2 = (j < o1) ? __expf(a - m) : 0.f;
            se += wl2;
            int wli = (int)h22u(__float2half2_rn(wl2));

            // ---- consume + prefetch, 24 edges per iteration ----
            for (int b = 0; b < cnt; b += 24) {
                #pragma unroll
                for (int q = 0; q < 8; q++) {
                    int wq = __builtin_amdgcn_readlane(wli, b + q);
                    acc2 = __hfma2(u2h2(ua[q]), u2h2((unsigned)wq), acc2);
                }
                if (b + 24 < cnt) {
                    #pragma unroll
                    for (int q = 0; q < 8; q++) {
                        int s = __builtin_amdgcn_readlane(sj, b + 24 + q);
                        ua[q] = Hh[(size_t)(unsigned)s * 64 + lane];
                    }
                }
                if (b + 8 < cnt) {
                    #pragma unroll
                    for (int q = 0; q < 8; q++) {
                        int wq = __builtin_amdgcn_readlane(wli, b + 8 + q);
                        acc2 = __hfma2(u2h2(ub[q]), u2h2((unsigned)wq), acc2);
                    }
                    if (b + 32 < cnt) {
                        #pragma unroll
                        for (int q = 0; q < 8; q++) {
                            int s = __builtin_amdgcn_readlane(sj, b + 32 + q);
                            ub[q] = Hh[(size_t)(unsigned)s * 64 + lane];
                        }
                    }
                    if (b + 16 < cnt) {
                        #pragma unroll
                        for (int q = 0; q < 8; q++) {
                            int wq = __builtin_amdgcn_readlane(wli, b + 16 + q);
                            acc2 = __hfma2(u2h2(uc[q]), u2h2((unsigned)wq), acc2);
                        }
                        if (b + 40 < cnt) {
                            #pragma unroll
                            for (int q = 0; q < 8; q++) {
                                int s = __builtin_amdgcn_readlane(sj, b + 40 + q);
                                uc[q] = Hh[(size_t)(unsigned)s * 64 + lane];
                            }
                        }
                    }
                }
            }
        }

        #pragma unroll
        for (int o = 32; o > 0; o >>= 1) se += __shfl_xor(se, o);
        float inv = 1.f / se;
        float2 af = __half22float2(acc2);
        float2 b2 = *(const float2*)(bias + lane * 2);
        rx = fmaf(af.x, inv, b2.x);
        ry = fmaf(af.y, inv, b2.y);
        unsigned pack = ((unsigned)(unsigned short)f2bf(ry) << 16) |
                        (unsigned)(unsigned short)f2bf(rx);
        Ob[(size_t)i * 64 + lane] = pack;
    }

    // ---- fused BN stats: block-level reduce then slotted atomics ----
    red[wid][lane][0] = rx;
    red[wid][lane][1] = ry;
    red[wid][lane][2] = rx * rx;
    red[wid][lane][3] = ry * ry;
    __syncthreads();
    if (threadIdx.x < 64) {
        int t2 = threadIdx.x;
        float a0 = 0.f, a1 = 0.f, a2 = 0.f, a3 = 0.f;
        #pragma unroll
        for (int g = 0; g < 4; g++) {
            a0 += red[g][t2][0]; a1 += red[g][t2][1];
            a2 += red[g][t2][2]; a3 += red[g][t2][3];
        }
        float* bp = bnout + (blockIdx.x & 7) * 256;
        atomicAdd(&bp[2 * t2],       a0);
        atomicAdd(&bp[2 * t2 + 1],   a1);
        atomicAdd(&bp[128 + 2 * t2], a2);
        atomicAdd(&bp[128 + 2 * t2 + 1], a3);
    }
}

// ---------------- classifier (MFMA): out = relu(bn(G)) @ Wc + bc -----------
__global__ __launch_bounds__(256) void k_cls(
    const unsigned* __restrict__ G, const short* __restrict__ Wtc,
    const float* __restrict__ bc, const float* __restrict__ bnsum,
    const float* __restrict__ gamma, const float* __restrict__ beta, float invn,
    float* __restrict__ out, int n)
{
    __shared__ short As[64 * 128];   // 16.4 KB
    __shared__ short Bs[48 * 128];   // 12.3 KB
    int t = threadIdx.x;
    int row0 = blockIdx.x * 64;

    for (int j = 0; j < 3; j++) {
        int idx = j * 256 + t;       // 768 short8 = 6144 shorts
        *(short8*)(Bs + idx * 8) = *(const short8*)(Wtc + idx * 8);
    }
    float4 sc4, sh4;
    bn_coeffs(bnsum, (t & 31) * 4, invn, gamma, beta, &sc4, &sh4);
    for (int j = 0; j < 8; j++) {
        int idx = j * 256 + t;
        int r = idx >> 5, k4 = idx & 31;
        int gr = row0 + r;
        float4 xv = make_float4(0.f, 0.f, 0.f, 0.f);
        if (gr < n) {
            uint2 u = *(const uint2*)(G + (size_t)gr * 64 + k4 * 2);
            xv.x = bf_lo(u.x); xv.y = bf_hi(u.x);
            xv.z = bf_lo(u.y); xv.w = bf_hi(u.y);
        }
        xv.x = fmaxf(fmaf(xv.x, sc4.x, sh4.x), 0.f);
        xv.y = fmaxf(fmaf(xv.y, sc4.y, sh4.y), 0.f);
        xv.z = fmaxf(fmaf(xv.z, sc4.z, sh4.z), 0.f);
        xv.w = fmaxf(fmaf(xv.w, sc4.w, sh4.w), 0.f);
        short4v o;
        o.x = f2bf(xv.x); o.y = f2bf(xv.y); o.z = f2bf(xv.z); o.w = f2bf(xv.w);
        *(short4v*)(As + r * 128 + k4 * 4) = o;
    }
    __syncthreads();

    int w = t >> 6, lane = t & 63, q = lane >> 4, c = lane & 15;
    f32x4 zero = {0.f, 0.f, 0.f, 0.f};
    f32x4 acc[3] = {zero, zero, zero};
    for (int ks = 0; ks < 4; ks++) {
        int k0 = ks * 32 + q * 8;
        short8 a  = *(short8*)(As + (w * 16 + c) * 128 + k0);
        short8 b0 = *(short8*)(Bs + (c) * 128 + k0);
        short8 b1 = *(short8*)(Bs + (16 + c) * 128 + k0);
        short8 b2 = *(short8*)(Bs + (32 + c) * 128 + k0);
        acc[0] = __builtin_amdgcn_mfma_f32_16x16x32_bf16(a, b0, acc[0], 0, 0, 0);
        acc[1] = __builtin_amdgcn_mfma_f32_16x16x32_bf16(a, b1, acc[1], 0, 0, 0);
        acc[2] = __builtin_amdgcn_mfma_f32_16x16x32_bf16(a, b2, acc[2], 0, 0, 0);
    }
    float bc0 = bc[c], bc1 = bc[16 + c], bc2 = (c < 8) ? bc[32 + c] : 0.f;
    #pragma unroll
    for (int r = 0; r < 4; r++) {
        int row = row0 + w * 16 + q * 4 + r;
        if (row < n) {
            out[(size_t)row * NCLS_ + c]      = acc[0][r] + bc0;
            out[(size_t)row * NCLS_ + 16 + c] = acc[1][r] + bc1;
            if (c < 8) out[(size_t)row * NCLS_ + 32 + c] = acc[2][r] + bc2;
        }
    }
}

// ---------------- launch ---------------------------------------------------
extern "C" void kernel_launch(void* const* d_in, const int* in_sizes, int n_in,
                              void* d_out, int out_size, void* d_ws, size_t ws_size,
                              hipStream_t stream)
{
    const float* x   = (const float*)d_in[0];
    const int*   ei  = (const int*)d_in[1];
    const float* W1  = (const float*)d_in[2];
    const float* as1 = (const float*)d_in[3];
    const float* ad1 = (const float*)d_in[4];
    const float* b1  = (const float*)d_in[5];
    const float* g1  = (const float*)d_in[6];
    const float* be1 = (const float*)d_in[7];
    const float* W2  = (const float*)d_in[8];
    const float* as2 = (const float*)d_in[9];
    const float* ad2 = (const float*)d_in[10];
    const float* b2  = (const float*)d_in[11];
    const float* g2  = (const float*)d_in[12];
    const float* be2 = (const float*)d_in[13];
    const float* Wc  = (const float*)d_in[14];
    const float* bc  = (const float*)d_in[15];
    float* out = (float*)d_out;

    int n = in_sizes[0] / CDIM;     // 100000
    int E = in_sizes[1] / 2;        // 1600000
    const int* src = ei;
    const int* dst = ei + E;
    float invn = 1.f / (float)n;
    int NB = (n + BRNG - 1) / BRNG; // 391

    // workspace layout (64B-aligned chunks)
    char* p = (char*)d_ws;
    auto alloc = [&p](size_t bytes) { char* q = p; p += (bytes + 63) & ~(size_t)63; return q; };
    short*    Hh      = (short*)alloc((size_t)n * CDIM * sizeof(short));
    unsigned* bufB    = (unsigned*)alloc((size_t)n * 64 * sizeof(unsigned));
    float*    alpha_s = (float*)alloc((size_t)n * sizeof(float));
    float*    alpha_d = (float*)alloc((size_t)n * sizeof(float));
    float*    bnsum   = (float*)alloc(4096 * sizeof(float));  // 2 x 8 slots x 256
    short*    Wt1     = (short*)alloc(128 * 128 * sizeof(short));
    short*    Wt2     = (short*)alloc(128 * 128 * sizeof(short));
    short*    Wtc     = (short*)alloc(48 * 128 * sizeof(short));
    short*    wsd1    = (short*)alloc(256 * sizeof(short));
    short*    wsd2    = (short*)alloc(256 * sizeof(short));
    int*      bcurs   = (int*)alloc((size_t)NB * sizeof(int));
    int*      offs    = (int*)alloc((size_t)(n + 1) * sizeof(int));
    uint2*    bucket  = (uint2*)alloc((size_t)NB * BCAP * sizeof(uint2));
    int*      csr     = (int*)alloc((size_t)(E + n) * sizeof(int));

    k_setup<<<dim3(64), dim3(256), 0, stream>>>(bcurs, bnsum, NB, n, E, offs,
                                                W1, W2, Wc, as1, ad1, as2, ad2,
                                                Wt1, Wt2, Wtc, wsd1, wsd2);

    int gemmN = (n + 63) / 64;            // 1563
    int binN  = (E + 4095) / 4096;        // 391
    // fat: layer-1 GEMM || edge binning (independent; both only need k_setup)
    k_pre<<<dim3(gemmN + binN), dim3(256), 0, stream>>>(
        x, Wt1, wsd1, Hh, alpha_s, alpha_d, n, gemmN,
        src, dst, E, bcurs, bucket, NB);

    k_fillB<<<dim3(NB), dim3(256), 0, stream>>>(bucket, bcurs, n, NB, offs, csr);

    dim3 ggrid(gemmN);
    dim3 wgrid((n + 3) / 4);

    // layer 1 aggregation (+ fused BN1 stats into bnsum[0..2047])
    k_agg<<<wgrid, 256, 0, stream>>>((const unsigned*)Hh, offs, csr, alpha_s, alpha_d,
                                     b1, bufB, bnsum, n);

    // layer 2 (BN1+relu folded into staging from 8-slot sums)
    k_gemm_mfma<<<ggrid, 256, 0, stream>>>(bufB, Wt2, wsd2, bnsum, g1, be1,
                                           invn, Hh, alpha_s, alpha_d, n);
    // layer 2 aggregation (+ fused BN2 stats into bnsum[2048..4095])
    k_agg<<<wgrid, 256, 0, stream>>>((const unsigned*)Hh, offs, csr, alpha_s, alpha_d,
                                     b2, bufB, bnsum + 2048, n);

    // classifier (MFMA, BN2+relu folded from 8-slot sums)
    k_cls<<<ggrid, 256, 0, stream>>>(bufB, Wtc, bc, bnsum + 2048, g2, be2, invn, out, n);
}

// Round 10
// 376.000 us; speedup vs baseline: 1.4636x; 1.4636x over previous
//
#include <hip/hip_runtime.h>
#include <hip/hip_fp16.h>
#include <math.h>

// GAT 2-layer + BN + classifier, MI355X.
// R20: R19's contended-atomic BN fusion reverted (measured: 3125 serialized
// RMW/address x ~31ns = +97us/dispatch). k_agg = R17 exact (67us floor).
// bnstats fixed in place instead: grid 256->2048 (R19 arithmetic showed
// ~30us each from 1-block/CU latency-bound loop), 32-slot atomic output
// (64 ops/address ~ 2us tail), consumers sum slots cooperatively via a
// 1KB LDS table. 9 launches as R17.

#define CDIM 128
#define NCLS_ 40
#define NEG_SLOPE_ 0.2f
#define BN_EPS_ 1e-5f
#define BRNG 256        // nodes per bucket (power of 2)
#define BCAP 6144       // max edges per bucket (mean 4096)
#define EPB 16          // edges per thread in binA phase (4096 per block)
#define NSLOT 32        // BN stat slots (atomic spread)

using short8  = __attribute__((ext_vector_type(8))) short;
using short4v = __attribute__((ext_vector_type(4))) short;
using f32x4   = __attribute__((ext_vector_type(4))) float;

static __device__ __forceinline__ float lrelu(float a) {
    return a > 0.f ? a : NEG_SLOPE_ * a;
}
// fp32 -> bf16 round-to-nearest-even
static __device__ __forceinline__ short f2bf(float f) {
    unsigned u = __float_as_uint(f);
    u += 0x7fffu + ((u >> 16) & 1u);
    return (short)(u >> 16);
}
static __device__ __forceinline__ float bf_lo(unsigned u) { return __uint_as_float(u << 16); }
static __device__ __forceinline__ float bf_hi(unsigned u) { return __uint_as_float(u & 0xffff0000u); }
static __device__ __forceinline__ __half2 u2h2(unsigned u) { return __builtin_bit_cast(__half2, u); }
static __device__ __forceinline__ unsigned h22u(__half2 h) { return __builtin_bit_cast(unsigned, h); }

// ---------------- setup: cursors=0, bn sums=0, offs[n], W->bf16^T, ws/wd ---
__global__ void k_setup(int* bcur, float* bnsum, int NB, int n, int E, int* offs,
                        const float* __restrict__ W1, const float* __restrict__ W2,
                        const float* __restrict__ Wc,
                        const float* __restrict__ as1, const float* __restrict__ ad1,
                        const float* __restrict__ as2, const float* __restrict__ ad2,
                        short* __restrict__ Wt1, short* __restrict__ Wt2,
                        short* __restrict__ Wtc,
                        short* __restrict__ wsd1, short* __restrict__ wsd2) {
    int i = blockIdx.x * blockDim.x + threadIdx.x;
    if (i < NB) bcur[i] = 0;
    if (i < 2 * NSLOT * 256) bnsum[i] = 0.f;   // 2 layers x 32 slots x 256
    if (i == 0) offs[n] = E + n;
    if (i < 128 * 128) {
        int k = i >> 7, nn = i & 127;
        Wt1[nn * 128 + k] = f2bf(W1[i]);
        Wt2[nn * 128 + k] = f2bf(W2[i]);
    }
    if (i < 48 * 128) {             // padded bf16 Wc^T [48][128]
        int nn = i >> 7, k = i & 127;
        Wtc[i] = (nn < NCLS_) ? f2bf(Wc[k * NCLS_ + nn]) : (short)0;
    }
    if (i < 128) {                  // ws = W @ a_s, wd = W @ a_d (both layers)
        float s1 = 0.f, d1 = 0.f, s2 = 0.f, d2 = 0.f;
        for (int nn2 = 0; nn2 < 128; nn2++) {
            float w1v = W1[i * 128 + nn2], w2v = W2[i * 128 + nn2];
            s1 = fmaf(w1v, as1[nn2], s1); d1 = fmaf(w1v, ad1[nn2], d1);
            s2 = fmaf(w2v, as2[nn2], s2); d2 = fmaf(w2v, ad2[nn2], d2);
        }
        wsd1[i] = f2bf(s1); wsd1[128 + i] = f2bf(d1);
        wsd2[i] = f2bf(s2); wsd2[128 + i] = f2bf(d2);
    }
}

// ---------------- FAT: layer-1 GEMM (blocks<gemmN) || edge binning ---------
__global__ __launch_bounds__(256) void k_pre(
    const float* __restrict__ Xf, const short* __restrict__ Wt,
    const short* __restrict__ wsd, short* __restrict__ Hh,
    float* __restrict__ alpha_s, float* __restrict__ alpha_d, int n, int gemmN,
    const int* __restrict__ src, const int* __restrict__ dst, int E,
    int* __restrict__ bcur, uint2* __restrict__ bucket, int NB)
{
    __shared__ union {
        struct { short As[64 * 128]; short Bs[128 * 128]; short wl[256]; } g;
        struct { int hist[400]; int base[400]; } b;
    } sm;
    int t = threadIdx.x;

    if (blockIdx.x >= gemmN) {
        // ---------------- binA body ----------------
        int bid = blockIdx.x - gemmN;
        int* hist = sm.b.hist;
        int* base = sm.b.base;
        long e0 = (long)bid * (256 * EPB) + t;

        for (int i = t; i < NB; i += 256) hist[i] = 0;
        __syncthreads();

        int sv[EPB], dv[EPB];
        #pragma unroll
        for (int i = 0; i < EPB; i++) {
            long e = e0 + (long)i * 256;
            if (e < E) {
                sv[i] = src[e]; dv[i] = dst[e];
                atomicAdd(&hist[dv[i] >> 8], 1);
            } else dv[i] = -1;
        }
        __syncthreads();

        for (int i = t; i < NB; i += 256) {
            int h = hist[i];
            base[i] = (h > 0) ? atomicAdd(&bcur[i], h) : 0;
        }
        __syncthreads();
        for (int i = t; i < NB; i += 256) hist[i] = 0;   // reuse as cursor
        __syncthreads();

        #pragma unroll
        for (int i = 0; i < EPB; i++) {
            if (dv[i] >= 0) {
                int b = dv[i] >> 8;
                int pos = base[b] + atomicAdd(&hist[b], 1);
                if (pos < BCAP)
                    bucket[(size_t)b * BCAP + pos] =
                        make_uint2((unsigned)sv[i], (unsigned)dv[i]);
            }
        }
        return;
    }

    // ---------------- layer-1 GEMM body (fp32 input, no BN fuse) ----------
    short* As = sm.g.As;
    short* Bs = sm.g.Bs;
    short* wl = sm.g.wl;
    int row0 = blockIdx.x * 64;

    for (int j = 0; j < 8; j++) {
        int idx = j * 256 + t;
        int nn = idx >> 4, cc = idx & 15;
        *(short8*)(Bs + nn * 128 + cc * 8) = *(const short8*)(Wt + nn * 128 + cc * 8);
    }
    if (t < 256) wl[t] = wsd[t];
    for (int j = 0; j < 8; j++) {
        int idx = j * 256 + t;
        int r = idx >> 5, k4 = idx & 31;
        int gr = row0 + r;
        float4 xv = make_float4(0.f, 0.f, 0.f, 0.f);
        if (gr < n) xv = *(const float4*)(Xf + (size_t)gr * CDIM + k4 * 4);
        short4v o;
        o.x = f2bf(xv.x); o.y = f2bf(xv.y); o.z = f2bf(xv.z); o.w = f2bf(xv.w);
        *(short4v*)(As + r * 128 + k4 * 4) = o;
    }
    __syncthreads();

    int w = t >> 6, lane = t & 63, q = lane >> 4, c = lane & 15;
    f32x4 zero = {0.f, 0.f, 0.f, 0.f};
    f32x4 acc[4][2];
    f32x4 acc_a = zero;               // alpha: col0=alpha_s, col1=alpha_d
    for (int i = 0; i < 4; i++) { acc[i][0] = zero; acc[i][1] = zero; }

    for (int ks = 0; ks < 4; ks++) {
        int k0 = ks * 32 + q * 8;
        short8 a0 = *(short8*)(As + (c) * 128 + k0);
        short8 a1 = *(short8*)(As + (16 + c) * 128 + k0);
        short8 a2 = *(short8*)(As + (32 + c) * 128 + k0);
        short8 a3 = *(short8*)(As + (48 + c) * 128 + k0);
        short8 b0 = *(short8*)(Bs + (w * 32 + c) * 128 + k0);
        short8 b1 = *(short8*)(Bs + (w * 32 + 16 + c) * 128 + k0);
        acc[0][0] = __builtin_amdgcn_mfma_f32_16x16x32_bf16(a0, b0, acc[0][0], 0, 0, 0);
        acc[1][0] = __builtin_amdgcn_mfma_f32_16x16x32_bf16(a1, b0, acc[1][0], 0, 0, 0);
        acc[2][0] = __builtin_amdgcn_mfma_f32_16x16x32_bf16(a2, b0, acc[2][0], 0, 0, 0);
        acc[3][0] = __builtin_amdgcn_mfma_f32_16x16x32_bf16(a3, b0, acc[3][0], 0, 0, 0);
        acc[0][1] = __builtin_amdgcn_mfma_f32_16x16x32_bf16(a0, b1, acc[0][1], 0, 0, 0);
        acc[1][1] = __builtin_amdgcn_mfma_f32_16x16x32_bf16(a1, b1, acc[1][1], 0, 0, 0);
        acc[2][1] = __builtin_amdgcn_mfma_f32_16x16x32_bf16(a2, b1, acc[2][1], 0, 0, 0);
        acc[3][1] = __builtin_amdgcn_mfma_f32_16x16x32_bf16(a3, b1, acc[3][1], 0, 0, 0);

        short8 ba;
        #pragma unroll
        for (int jj = 0; jj < 8; jj++) {
            short vs = wl[k0 + jj], vd = wl[128 + k0 + jj];
            ba[jj] = (c == 0) ? vs : ((c == 1) ? vd : (short)0);
        }
        short8 aw = (w == 0) ? a0 : ((w == 1) ? a1 : ((w == 2) ? a2 : a3));
        acc_a = __builtin_amdgcn_mfma_f32_16x16x32_bf16(aw, ba, acc_a, 0, 0, 0);
    }

    __syncthreads();                  // all As reads done before reuse

    short* Hs = As;
    #pragma unroll
    for (int mt = 0; mt < 4; mt++)
        #pragma unroll
        for (int nt = 0; nt < 2; nt++)
            #pragma unroll
            for (int r = 0; r < 4; r++)
                Hs[(mt * 16 + q * 4 + r) * 128 + w * 32 + nt * 16 + c] =
                    (short)__half_as_ushort(__float2half_rn(acc[mt][nt][r]));

    if (c < 2) {
        #pragma unroll
        for (int r = 0; r < 4; r++) {
            int row = row0 + w * 16 + q * 4 + r;
            if (row < n) {
                if (c == 0) alpha_s[row] = acc_a[r];
                else        alpha_d[row] = acc_a[r];
            }
        }
    }
    __syncthreads();

    for (int j = 0; j < 4; j++) {
        int idx = j * 256 + t;
        int r = idx >> 4, cc = idx & 15;
        int gr = row0 + r;
        if (gr < n)
            *(short8*)(Hh + (size_t)gr * 128 + cc * 8) = *(short8*)(Hs + r * 128 + cc * 8);
    }
}

// ---------------- per-bucket CSR build in LDS ------------------------------
__global__ __launch_bounds__(256) void k_fillB(
    const uint2* __restrict__ bucket, const int* __restrict__ bcur,
    int n, int NB, int* __restrict__ offs, int* __restrict__ csr)
{
    __shared__ int hist[256];
    __shared__ int scanb[256];
    __shared__ int cur[256];
    __shared__ int buf[BCAP + BRNG];
    int b = blockIdx.x, t = threadIdx.x;
    int node0 = b << 8;
    int nodesIn = min(BRNG, n - node0);
    int cnt = min(bcur[b], BCAP);
    const uint2* mybkt = bucket + (size_t)b * BCAP;

    int part = 0;
    for (int j = t; j < b; j += 256) part += min(bcur[j], BCAP);
    scanb[t] = part; __syncthreads();
    for (int s2 = 128; s2 > 0; s2 >>= 1) {
        if (t < s2) scanb[t] += scanb[t + s2];
        __syncthreads();
    }
    int base = scanb[0] + node0;
    __syncthreads();

    hist[t] = 0; __syncthreads();
    for (int e2 = t; e2 < cnt; e2 += 256)
        atomicAdd(&hist[mybkt[e2].y & 255], 1);
    __syncthreads();

    int v = hist[t] + ((t < nodesIn) ? 1 : 0);
    scanb[t] = v; __syncthreads();
    for (int d = 1; d < 256; d <<= 1) {
        int x2 = (t >= d) ? scanb[t - d] : 0;
        __syncthreads();
        scanb[t] += x2;
        __syncthreads();
    }
    int lo = scanb[t] - v;
    if (t < nodesIn) {
        offs[node0 + t] = base + lo;
        buf[lo] = node0 + t;          // self-loop occupies slot 0
        cur[t] = lo + 1;
    }
    __syncthreads();

    for (int e2 = t; e2 < cnt; e2 += 256) {
        uint2 ed = mybkt[e2];
        int pos = atomicAdd(&cur[ed.y & 255], 1);
        buf[pos] = (int)ed.x;
    }
    __syncthreads();

    int tot = cnt + nodesIn;
    for (int j2 = t; j2 < tot; j2 += 256) csr[base + j2] = buf[j2];
}

// ---------------- MFMA GEMM (layer 2): Hh = act(bn(G)) @ W, alpha fused ----
__global__ __launch_bounds__(256) void k_gemm_mfma(
    const unsigned* __restrict__ Xb, const short* __restrict__ Wt,
    const short* __restrict__ wsd,
    const float* __restrict__ bnsum, const float* __restrict__ gamma,
    const float* __restrict__ beta, float invn,
    short* __restrict__ Hh, float* __restrict__ alpha_s, float* __restrict__ alpha_d,
    int n)
{
    __shared__ short As[64 * 128];    // 16.4 KB (reused as H transpose buffer)
    __shared__ short Bs[128 * 128];   // 32.8 KB
    __shared__ short wl[256];         // ws (0..127), wd (128..255) bf16
    __shared__ float bnl[256];        // slot-summed BN stats
    int t = threadIdx.x;
    int row0 = blockIdx.x * 64;

    for (int j = 0; j < 8; j++) {
        int idx = j * 256 + t;
        int nn = idx >> 4, cc = idx & 15;
        *(short8*)(Bs + nn * 128 + cc * 8) = *(const short8*)(Wt + nn * 128 + cc * 8);
    }
    if (t < 256) wl[t] = wsd[t];
    // cooperative 32-slot reduction: thread t sums stat-index t
    {
        float s = 0.f;
        #pragma unroll
        for (int sl = 0; sl < NSLOT; sl++) s += bnsum[sl * 256 + t];
        bnl[t] = s;
    }
    __syncthreads();
    float4 sc4, sh4;
    {
        int cb = (t & 31) * 4;
        float mean, var;
        mean = bnl[cb + 0] * invn; var = fmaxf(bnl[128 + cb + 0] * invn - mean * mean, 0.f);
        sc4.x = gamma[cb + 0] * rsqrtf(var + BN_EPS_); sh4.x = beta[cb + 0] - mean * sc4.x;
        mean = bnl[cb + 1] * invn; var = fmaxf(bnl[128 + cb + 1] * invn - mean * mean, 0.f);
        sc4.y = gamma[cb + 1] * rsqrtf(var + BN_EPS_); sh4.y = beta[cb + 1] - mean * sc4.y;
        mean = bnl[cb + 2] * invn; var = fmaxf(bnl[128 + cb + 2] * invn - mean * mean, 0.f);
        sc4.z = gamma[cb + 2] * rsqrtf(var + BN_EPS_); sh4.z = beta[cb + 2] - mean * sc4.z;
        mean = bnl[cb + 3] * invn; var = fmaxf(bnl[128 + cb + 3] * invn - mean * mean, 0.f);
        sc4.w = gamma[cb + 3] * rsqrtf(var + BN_EPS_); sh4.w = beta[cb + 3] - mean * sc4.w;
    }
    for (int j = 0; j < 8; j++) {
        int idx = j * 256 + t;
        int r = idx >> 5, k4 = idx & 31;
        int gr = row0 + r;
        float4 xv = make_float4(0.f, 0.f, 0.f, 0.f);
        if (gr < n) {
            uint2 u = *(const uint2*)(Xb + (size_t)gr * 64 + k4 * 2);
            xv.x = bf_lo(u.x); xv.y = bf_hi(u.x);
            xv.z = bf_lo(u.y); xv.w = bf_hi(u.y);
        }
        xv.x = fmaxf(fmaf(xv.x, sc4.x, sh4.x), 0.f);
        xv.y = fmaxf(fmaf(xv.y, sc4.y, sh4.y), 0.f);
        xv.z = fmaxf(fmaf(xv.z, sc4.z, sh4.z), 0.f);
        xv.w = fmaxf(fmaf(xv.w, sc4.w, sh4.w), 0.f);
        short4v o;
        o.x = f2bf(xv.x); o.y = f2bf(xv.y); o.z = f2bf(xv.z); o.w = f2bf(xv.w);
        *(short4v*)(As + r * 128 + k4 * 4) = o;
    }
    __syncthreads();

    int w = t >> 6, lane = t & 63, q = lane >> 4, c = lane & 15;
    f32x4 zero = {0.f, 0.f, 0.f, 0.f};
    f32x4 acc[4][2];
    f32x4 acc_a = zero;
    for (int i = 0; i < 4; i++) { acc[i][0] = zero; acc[i][1] = zero; }

    for (int ks = 0; ks < 4; ks++) {
        int k0 = ks * 32 + q * 8;
        short8 a0 = *(short8*)(As + (c) * 128 + k0);
        short8 a1 = *(short8*)(As + (16 + c) * 128 + k0);
        short8 a2 = *(short8*)(As + (32 + c) * 128 + k0);
        short8 a3 = *(short8*)(As + (48 + c) * 128 + k0);
        short8 b0 = *(short8*)(Bs + (w * 32 + c) * 128 + k0);
        short8 b1 = *(short8*)(Bs + (w * 32 + 16 + c) * 128 + k0);
        acc[0][0] = __builtin_amdgcn_mfma_f32_16x16x32_bf16(a0, b0, acc[0][0], 0, 0, 0);
        acc[1][0] = __builtin_amdgcn_mfma_f32_16x16x32_bf16(a1, b0, acc[1][0], 0, 0, 0);
        acc[2][0] = __builtin_amdgcn_mfma_f32_16x16x32_bf16(a2, b0, acc[2][0], 0, 0, 0);
        acc[3][0] = __builtin_amdgcn_mfma_f32_16x16x32_bf16(a3, b0, acc[3][0], 0, 0, 0);
        acc[0][1] = __builtin_amdgcn_mfma_f32_16x16x32_bf16(a0, b1, acc[0][1], 0, 0, 0);
        acc[1][1] = __builtin_amdgcn_mfma_f32_16x16x32_bf16(a1, b1, acc[1][1], 0, 0, 0);
        acc[2][1] = __builtin_amdgcn_mfma_f32_16x16x32_bf16(a2, b1, acc[2][1], 0, 0, 0);
        acc[3][1] = __builtin_amdgcn_mfma_f32_16x16x32_bf16(a3, b1, acc[3][1], 0, 0, 0);

        short8 ba;
        #pragma unroll
        for (int jj = 0; jj < 8; jj++) {
            short vs = wl[k0 + jj], vd = wl[128 + k0 + jj];
            ba[jj] = (c == 0) ? vs : ((c == 1) ? vd : (short)0);
        }
        short8 aw = (w == 0) ? a0 : ((w == 1) ? a1 : ((w == 2) ? a2 : a3));
        acc_a = __builtin_amdgcn_mfma_f32_16x16x32_bf16(aw, ba, acc_a, 0, 0, 0);
    }

    __syncthreads();

    short* Hs = As;
    #pragma unroll
    for (int mt = 0; mt < 4; mt++)
        #pragma unroll
        for (int nt = 0; nt < 2; nt++)
            #pragma unroll
            for (int r = 0; r < 4; r++)
                Hs[(mt * 16 + q * 4 + r) * 128 + w * 32 + nt * 16 + c] =
                    (short)__half_as_ushort(__float2half_rn(acc[mt][nt][r]));

    if (c < 2) {
        #pragma unroll
        for (int r = 0; r < 4; r++) {
            int row = row0 + w * 16 + q * 4 + r;
            if (row < n) {
                if (c == 0) alpha_s[row] = acc_a[r];
                else        alpha_d[row] = acc_a[r];
            }
        }
    }
    __syncthreads();

    for (int j = 0; j < 4; j++) {
        int idx = j * 256 + t;
        int r = idx >> 4, cc = idx & 15;
        int gr = row0 + r;
        if (gr < n)
            *(short8*)(Hh + (size_t)gr * 128 + cc * 8) = *(short8*)(Hs + r * 128 + cc * 8);
    }
}

// ---------------- ONE-PASS softmax + aggregation (one wave per node) -------
// R11/R17 exact: all <=24 row-gathers issued BEFORE the alpha gather +
// softmax (loads depend only on sj), 3-deep batch pipeline for degree>24.
__global__ __launch_bounds__(256) void k_agg(
    const unsigned* __restrict__ Hh, const int* __restrict__ offs,
    const int* __restrict__ csr, const float* __restrict__ alpha_s,
    const float* __restrict__ alpha_d, const float* __restrict__ bias,
    unsigned* __restrict__ Ob, int n)
{
    int i = blockIdx.x * 4 + (threadIdx.x >> 6);
    int lane = threadIdx.x & 63;
    if (i >= n) return;
    int o0 = offs[i], o1 = offs[i + 1];
    float adi = alpha_d[i];

    float m = -1e30f;
    float se = 0.f;
    __half2 acc2 = __floats2half2_rn(0.f, 0.f);

    for (int c0 = o0; c0 < o1; c0 += 64) {
        int j = c0 + lane;
        int cnt = min(64, o1 - c0);
        int sj = (j < o1) ? csr[j] : 0;   // invalid lanes -> row 0 (w=0)

        // ---- issue up to 24 H-row gathers now (independent of weights) ----
        unsigned ua[8], ub[8], uc[8];
        #pragma unroll
        for (int q = 0; q < 8; q++) {
            int s = __builtin_amdgcn_readlane(sj, q);
            ua[q] = Hh[(size_t)(unsigned)s * 64 + lane];
        }
        if (cnt > 8) {
            #pragma unroll
            for (int q = 0; q < 8; q++) {
                int s = __builtin_amdgcn_readlane(sj, 8 + q);
                ub[q] = Hh[(size_t)(unsigned)s * 64 + lane];
            }
        }
        if (cnt > 16) {
            #pragma unroll
            for (int q = 0; q < 8; q++) {
                int s = __builtin_amdgcn_readlane(sj, 16 + q);
                uc[q] = Hh[(size_t)(unsigned)s * 64 + lane];
            }
        }

        // ---- softmax weights (overlaps the in-flight gathers) ----
        float a = (j < o1) ? lrelu(alpha_s[sj] + adi) : -1e30f;
        float cm = a;
        #pragma unroll
        for (int o = 32; o > 0; o >>= 1) cm = fmaxf(cm, __shfl_xor(cm, o));
        if (cm > m) {
            float r = __expf(m - cm);
            se *= r;
            acc2 = __hmul2(acc2, __float2half2_rn(r));
            m = cm;
        }
        float wl2 = (j < o1) ? __expf(a - m) : 0.f;
        se += wl2;
        int wli = (int)h22u(__float2half2_rn(wl2));

        // ---- consume + prefetch, 24 edges per iteration ----
        for (int b = 0; b < cnt; b += 24) {
            #pragma unroll
            for (int q = 0; q < 8; q++) {
                int wq = __builtin_amdgcn_readlane(wli, b + q);
                acc2 = __hfma2(u2h2(ua[q]), u2h2((unsigned)wq), acc2);
            }
            if (b + 24 < cnt) {
                #pragma unroll
                for (int q = 0; q < 8; q++) {
                    int s = __builtin_amdgcn_readlane(sj, b + 24 + q);
                    ua[q] = Hh[(size_t)(unsigned)s * 64 + lane];
                }
            }
            if (b + 8 < cnt) {
                #pragma unroll
                for (int q = 0; q < 8; q++) {
                    int wq = __builtin_amdgcn_readlane(wli, b + 8 + q);
                    acc2 = __hfma2(u2h2(ub[q]), u2h2((unsigned)wq), acc2);
                }
                if (b + 32 < cnt) {
                    #pragma unroll
                    for (int q = 0; q < 8; q++) {
                        int s = __builtin_amdgcn_readlane(sj, b + 32 + q);
                        ub[q] = Hh[(size_t)(unsigned)s * 64 + lane];
                    }
                }
                if (b + 16 < cnt) {
                    #pragma unroll
                    for (int q = 0; q < 8; q++) {
                        int wq = __builtin_amdgcn_readlane(wli, b + 16 + q);
                        acc2 = __hfma2(u2h2(uc[q]), u2h2((unsigned)wq), acc2);
                    }
                    if (b + 40 < cnt) {
                        #pragma unroll
                        for (int q = 0; q < 8; q++) {
                            int s = __builtin_amdgcn_readlane(sj, b + 40 + q);
                            uc[q] = Hh[(size_t)(unsigned)s * 64 + lane];
                        }
                    }
                }
            }
        }
    }

    #pragma unroll
    for (int o = 32; o > 0; o >>= 1) se += __shfl_xor(se, o);
    float inv = 1.f / se;
    float2 af = __half22float2(acc2);
    float2 b2 = *(const float2*)(bias + lane * 2);
    float rx = fmaf(af.x, inv, b2.x);
    float ry = fmaf(af.y, inv, b2.y);
    unsigned pack = ((unsigned)(unsigned short)f2bf(ry) << 16) |
                    (unsigned)(unsigned short)f2bf(rx);
    Ob[(size_t)i * 64 + lane] = pack;
}

// ---------------- BN stats: grid-stride, 32-slot atomic output -------------
// grid 2048 (8 blocks/CU: latency hiding), slot = blockIdx&31 ->
// 64 atomics/address (~2us tail vs R19's 3125 -> 97us).
__global__ __launch_bounds__(256) void k_bnstats(
    const unsigned* __restrict__ Hb, int n, float* __restrict__ sums)
{
    __shared__ float red[4][64][4];
    int w = threadIdx.x & 63;
    int g = threadIdx.x >> 6;
    float slo = 0.f, shi = 0.f, qlo = 0.f, qhi = 0.f;
    for (int r = blockIdx.x * 4 + g; r < n; r += gridDim.x * 4) {
        unsigned u = Hb[(size_t)r * 64 + w];
        float lo = bf_lo(u), hi = bf_hi(u);
        slo += lo; shi += hi; qlo += lo * lo; qhi += hi * hi;
    }
    red[g][w][0] = slo; red[g][w][1] = shi; red[g][w][2] = qlo; red[g][w][3] = qhi;
    __syncthreads();
    if (threadIdx.x < 64) {
        int w2 = threadIdx.x;
        float s0 = 0.f, s1 = 0.f, s2 = 0.f, s3 = 0.f;
        for (int gg = 0; gg < 4; gg++) {
            s0 += red[gg][w2][0]; s1 += red[gg][w2][1];
            s2 += red[gg][w2][2]; s3 += red[gg][w2][3];
        }
        float* bp = sums + (blockIdx.x & (NSLOT - 1)) * 256;
        atomicAdd(&bp[2 * w2], s0);
        atomicAdd(&bp[2 * w2 + 1], s1);
        atomicAdd(&bp[128 + 2 * w2], s2);
        atomicAdd(&bp[128 + 2 * w2 + 1], s3);
    }
}

// ---------------- classifier (MFMA): out = relu(bn(G)) @ Wc + bc -----------
__global__ __launch_bounds__(256) void k_cls(
    const unsigned* __restrict__ G, const short* __restrict__ Wtc,
    const float* __restrict__ bc, const float* __restrict__ bnsum,
    const float* __restrict__ gamma, const float* __restrict__ beta, float invn,
    float* __restrict__ out, int n)
{
    __shared__ short As[64 * 128];   // 16.4 KB
    __shared__ short Bs[48 * 128];   // 12.3 KB
    __shared__ float bnl[256];
    int t = threadIdx.x;
    int row0 = blockIdx.x * 64;

    for (int j = 0; j < 3; j++) {
        int idx = j * 256 + t;       // 768 short8 = 6144 shorts
        *(short8*)(Bs + idx * 8) = *(const short8*)(Wtc + idx * 8);
    }
    // cooperative 32-slot reduction
    {
        float s = 0.f;
        #pragma unroll
        for (int sl = 0; sl < NSLOT; sl++) s += bnsum[sl * 256 + t];
        bnl[t] = s;
    }
    __syncthreads();
    float4 sc4, sh4;
    {
        int cb = (t & 31) * 4;
        float mean, var;
        mean = bnl[cb + 0] * invn; var = fmaxf(bnl[128 + cb + 0] * invn - mean * mean, 0.f);
        sc4.x = gamma[cb + 0] * rsqrtf(var + BN_EPS_); sh4.x = beta[cb + 0] - mean * sc4.x;
        mean = bnl[cb + 1] * invn; var = fmaxf(bnl[128 + cb + 1] * invn - mean * mean, 0.f);
        sc4.y = gamma[cb + 1] * rsqrtf(var + BN_EPS_); sh4.y = beta[cb + 1] - mean * sc4.y;
        mean = bnl[cb + 2] * invn; var = fmaxf(bnl[128 + cb + 2] * invn - mean * mean, 0.f);
        sc4.z = gamma[cb + 2] * rsqrtf(var + BN_EPS_); sh4.z = beta[cb + 2] - mean * sc4.z;
        mean = bnl[cb + 3] * invn; var = fmaxf(bnl[128 + cb + 3] * invn - mean * mean, 0.f);
        sc4.w = gamma[cb + 3] * rsqrtf(var + BN_EPS_); sh4.w = beta[cb + 3] - mean * sc4.w;
    }
    for (int j = 0; j < 8; j++) {
        int idx = j * 256 + t;
        int r = idx >> 5, k4 = idx & 31;
        int gr = row0 + r;
        float4 xv = make_float4(0.f, 0.f, 0.f, 0.f);
        if (gr < n) {
            uint2 u = *(const uint2*)(G + (size_t)gr * 64 + k4 * 2);
            xv.x = bf_lo(u.x); xv.y = bf_hi(u.x);
            xv.z = bf_lo(u.y); xv.w = bf_hi(u.y);
        }
        xv.x = fmaxf(fmaf(xv.x, sc4.x, sh4.x), 0.f);
        xv.y = fmaxf(fmaf(xv.y, sc4.y, sh4.y), 0.f);
        xv.z = fmaxf(fmaf(xv.z, sc4.z, sh4.z), 0.f);
        xv.w = fmaxf(fmaf(xv.w, sc4.w, sh4.w), 0.f);
        short4v o;
        o.x = f2bf(xv.x); o.y = f2bf(xv.y); o.z = f2bf(xv.z); o.w = f2bf(xv.w);
        *(short4v*)(As + r * 128 + k4 * 4) = o;
    }
    __syncthreads();

    int w = t >> 6, lane = t & 63, q = lane >> 4, c = lane & 15;
    f32x4 zero = {0.f, 0.f, 0.f, 0.f};
    f32x4 acc[3] = {zero, zero, zero};
    for (int ks = 0; ks < 4; ks++) {
        int k0 = ks * 32 + q * 8;
        short8 a  = *(short8*)(As + (w * 16 + c) * 128 + k0);
        short8 b0 = *(short8*)(Bs + (c) * 128 + k0);
        short8 b1 = *(short8*)(Bs + (16 + c) * 128 + k0);
        short8 b2 = *(short8*)(Bs + (32 + c) * 128 + k0);
        acc[0] = __builtin_amdgcn_mfma_f32_16x16x32_bf16(a, b0, acc[0], 0, 0, 0);
        acc[1] = __builtin_amdgcn_mfma_f32_16x16x32_bf16(a, b1, acc[1], 0, 0, 0);
        acc[2] = __builtin_amdgcn_mfma_f32_16x16x32_bf16(a, b2, acc[2], 0, 0, 0);
    }
    float bc0 = bc[c], bc1 = bc[16 + c], bc2 = (c < 8) ? bc[32 + c] : 0.f;
    #pragma unroll
    for (int r = 0; r < 4; r++) {
        int row = row0 + w * 16 + q * 4 + r;
        if (row < n) {
            out[(size_t)row * NCLS_ + c]      = acc[0][r] + bc0;
            out[(size_t)row * NCLS_ + 16 + c] = acc[1][r] + bc1;
            if (c < 8) out[(size_t)row * NCLS_ + 32 + c] = acc[2][r] + bc2;
        }
    }
}

// ---------------- launch ---------------------------------------------------
extern "C" void kernel_launch(void* const* d_in, const int* in_sizes, int n_in,
                              void* d_out, int out_size, void* d_ws, size_t ws_size,
                              hipStream_t stream)
{
    const float* x   = (const float*)d_in[0];
    const int*   ei  = (const int*)d_in[1];
    const float* W1  = (const float*)d_in[2];
    const float* as1 = (const float*)d_in[3];
    const float* ad1 = (const float*)d_in[4];
    const float* b1  = (const float*)d_in[5];
    const float* g1  = (const float*)d_in[6];
    const float* be1 = (const float*)d_in[7];
    const float* W2  = (const float*)d_in[8];
    const float* as2 = (const float*)d_in[9];
    const float* ad2 = (const float*)d_in[10];
    const float* b2  = (const float*)d_in[11];
    const float* g2  = (const float*)d_in[12];
    const float* be2 = (const float*)d_in[13];
    const float* Wc  = (const float*)d_in[14];
    const float* bc  = (const float*)d_in[15];
    float* out = (float*)d_out;

    int n = in_sizes[0] / CDIM;     // 100000
    int E = in_sizes[1] / 2;        // 1600000
    const int* src = ei;
    const int* dst = ei + E;
    float invn = 1.f / (float)n;
    int NB = (n + BRNG - 1) / BRNG; // 391

    // workspace layout (64B-aligned chunks)
    char* p = (char*)d_ws;
    auto alloc = [&p](size_t bytes) { char* q = p; p += (bytes + 63) & ~(size_t)63; return q; };
    short*    Hh      = (short*)alloc((size_t)n * CDIM * sizeof(short));
    unsigned* bufB    = (unsigned*)alloc((size_t)n * 64 * sizeof(unsigned));
    float*    alpha_s = (float*)alloc((size_t)n * sizeof(float));
    float*    alpha_d = (float*)alloc((size_t)n * sizeof(float));
    float*    bnsum   = (float*)alloc(2 * NSLOT * 256 * sizeof(float)); // 64 KB
    short*    Wt1     = (short*)alloc(128 * 128 * sizeof(short));
    short*    Wt2     = (short*)alloc(128 * 128 * sizeof(short));
    short*    Wtc     = (short*)alloc(48 * 128 * sizeof(short));
    short*    wsd1    = (short*)alloc(256 * sizeof(short));
    short*    wsd2    = (short*)alloc(256 * sizeof(short));
    int*      bcurs   = (int*)alloc((size_t)NB * sizeof(int));
    int*      offs    = (int*)alloc((size_t)(n + 1) * sizeof(int));
    uint2*    bucket  = (uint2*)alloc((size_t)NB * BCAP * sizeof(uint2));
    int*      csr     = (int*)alloc((size_t)(E + n) * sizeof(int));

    k_setup<<<dim3(64), dim3(256), 0, stream>>>(bcurs, bnsum, NB, n, E, offs,
                                                W1, W2, Wc, as1, ad1, as2, ad2,
                                                Wt1, Wt2, Wtc, wsd1, wsd2);

    int gemmN = (n + 63) / 64;            // 1563
    int binN  = (E + 4095) / 4096;        // 391
    // fat: layer-1 GEMM || edge binning (independent; both only need k_setup)
    k_pre<<<dim3(gemmN + binN), dim3(256), 0, stream>>>(
        x, Wt1, wsd1, Hh, alpha_s, alpha_d, n, gemmN,
        src, dst, E, bcurs, bucket, NB);

    k_fillB<<<dim3(NB), dim3(256), 0, stream>>>(bucket, bcurs, n, NB, offs, csr);

    dim3 ggrid(gemmN);
    dim3 wgrid((n + 3) / 4);

    // layer 1 aggregation + BN1 stats (grid-stride, 32-slot)
    k_agg<<<wgrid, 256, 0, stream>>>((const unsigned*)Hh, offs, csr, alpha_s, alpha_d,
                                     b1, bufB, n);
    k_bnstats<<<dim3(2048), dim3(256), 0, stream>>>(bufB, n, bnsum);

    // layer 2 (BN1+relu folded into staging from 32-slot sums)
    k_gemm_mfma<<<ggrid, 256, 0, stream>>>(bufB, Wt2, wsd2, bnsum, g1, be1,
                                           invn, Hh, alpha_s, alpha_d, n);
    k_agg<<<wgrid, 256, 0, stream>>>((const unsigned*)Hh, offs, csr, alpha_s, alpha_d,
                                     b2, bufB, n);
    k_bnstats<<<dim3(2048), dim3(256), 0, stream>>>(bufB, n, bnsum + NSLOT * 256);

    // classifier (MFMA, BN2+relu folded from 32-slot sums)
    k_cls<<<ggrid, 256, 0, stream>>>(bufB, Wtc, bc, bnsum + NSLOT * 256, g2, be2,
                                     invn, out, n);
}

// Round 12
// 375.479 us; speedup vs baseline: 1.4656x; 1.0014x over previous
//
#include <hip/hip_runtime.h>
#include <hip/hip_fp16.h>
#include <hip/hip_cooperative_groups.h>
#include <math.h>

// GAT 2-layer + BN + classifier, MI355X.
// R22 = R21 + capture gate. R21's container death was plausibly caused by
// hipLaunchCooperativeKernel inside a capturing stream (capture invalidation
// -> cascading launch failures) or coop-in-graph replay hang. Fix: query
// hipStreamIsCapturing FIRST; cooperative fusion only when NOT capturing.
// When capturing, take the byte-identical R20 path (known-good 376us).
//   coop1 = {agg1 -> grid.sync -> bnstats1}                (LDS 4KB)
//   coop2 = {agg2 -> grid.sync -> bnstats2 -> sync -> cls} (LDS 29.7KB)
// All phase bodies are the verified R20 bodies factored into __device__ fns.

namespace cg = cooperative_groups;

#define CDIM 128
#define NCLS_ 40
#define NEG_SLOPE_ 0.2f
#define BN_EPS_ 1e-5f
#define BRNG 256        // nodes per bucket (power of 2)
#define BCAP 6144       // max edges per bucket (mean 4096)
#define EPB 16          // edges per thread in binA phase (4096 per block)
#define NSLOT 32        // BN stat slots (atomic spread)

using short8  = __attribute__((ext_vector_type(8))) short;
using short4v = __attribute__((ext_vector_type(4))) short;
using f32x4   = __attribute__((ext_vector_type(4))) float;

static __device__ __forceinline__ float lrelu(float a) {
    return a > 0.f ? a : NEG_SLOPE_ * a;
}
// fp32 -> bf16 round-to-nearest-even
static __device__ __forceinline__ short f2bf(float f) {
    unsigned u = __float_as_uint(f);
    u += 0x7fffu + ((u >> 16) & 1u);
    return (short)(u >> 16);
}
static __device__ __forceinline__ float bf_lo(unsigned u) { return __uint_as_float(u << 16); }
static __device__ __forceinline__ float bf_hi(unsigned u) { return __uint_as_float(u & 0xffff0000u); }
static __device__ __forceinline__ __half2 u2h2(unsigned u) { return __builtin_bit_cast(__half2, u); }
static __device__ __forceinline__ unsigned h22u(__half2 h) { return __builtin_bit_cast(unsigned, h); }

// ---------------- setup: cursors=0, bn sums=0, offs[n], W->bf16^T, ws/wd ---
__global__ void k_setup(int* bcur, float* bnsum, int NB, int n, int E, int* offs,
                        const float* __restrict__ W1, const float* __restrict__ W2,
                        const float* __restrict__ Wc,
                        const float* __restrict__ as1, const float* __restrict__ ad1,
                        const float* __restrict__ as2, const float* __restrict__ ad2,
                        short* __restrict__ Wt1, short* __restrict__ Wt2,
                        short* __restrict__ Wtc,
                        short* __restrict__ wsd1, short* __restrict__ wsd2) {
    int i = blockIdx.x * blockDim.x + threadIdx.x;
    if (i < NB) bcur[i] = 0;
    if (i < 2 * NSLOT * 256) bnsum[i] = 0.f;   // 2 layers x 32 slots x 256
    if (i == 0) offs[n] = E + n;
    if (i < 128 * 128) {
        int k = i >> 7, nn = i & 127;
        Wt1[nn * 128 + k] = f2bf(W1[i]);
        Wt2[nn * 128 + k] = f2bf(W2[i]);
    }
    if (i < 48 * 128) {             // padded bf16 Wc^T [48][128]
        int nn = i >> 7, k = i & 127;
        Wtc[i] = (nn < NCLS_) ? f2bf(Wc[k * NCLS_ + nn]) : (short)0;
    }
    if (i < 128) {                  // ws = W @ a_s, wd = W @ a_d (both layers)
        float s1 = 0.f, d1 = 0.f, s2 = 0.f, d2 = 0.f;
        for (int nn2 = 0; nn2 < 128; nn2++) {
            float w1v = W1[i * 128 + nn2], w2v = W2[i * 128 + nn2];
            s1 = fmaf(w1v, as1[nn2], s1); d1 = fmaf(w1v, ad1[nn2], d1);
            s2 = fmaf(w2v, as2[nn2], s2); d2 = fmaf(w2v, ad2[nn2], d2);
        }
        wsd1[i] = f2bf(s1); wsd1[128 + i] = f2bf(d1);
        wsd2[i] = f2bf(s2); wsd2[128 + i] = f2bf(d2);
    }
}

// ---------------- FAT: layer-1 GEMM (blocks<gemmN) || edge binning ---------
__global__ __launch_bounds__(256) void k_pre(
    const float* __restrict__ Xf, const short* __restrict__ Wt,
    const short* __restrict__ wsd, short* __restrict__ Hh,
    float* __restrict__ alpha_s, float* __restrict__ alpha_d, int n, int gemmN,
    const int* __restrict__ src, const int* __restrict__ dst, int E,
    int* __restrict__ bcur, uint2* __restrict__ bucket, int NB)
{
    __shared__ union {
        struct { short As[64 * 128]; short Bs[128 * 128]; short wl[256]; } g;
        struct { int hist[400]; int base[400]; } b;
    } sm;
    int t = threadIdx.x;

    if (blockIdx.x >= gemmN) {
        // ---------------- binA body ----------------
        int bid = blockIdx.x - gemmN;
        int* hist = sm.b.hist;
        int* base = sm.b.base;
        long e0 = (long)bid * (256 * EPB) + t;

        for (int i = t; i < NB; i += 256) hist[i] = 0;
        __syncthreads();

        int sv[EPB], dv[EPB];
        #pragma unroll
        for (int i = 0; i < EPB; i++) {
            long e = e0 + (long)i * 256;
            if (e < E) {
                sv[i] = src[e]; dv[i] = dst[e];
                atomicAdd(&hist[dv[i] >> 8], 1);
            } else dv[i] = -1;
        }
        __syncthreads();

        for (int i = t; i < NB; i += 256) {
            int h = hist[i];
            base[i] = (h > 0) ? atomicAdd(&bcur[i], h) : 0;
        }
        __syncthreads();
        for (int i = t; i < NB; i += 256) hist[i] = 0;   // reuse as cursor
        __syncthreads();

        #pragma unroll
        for (int i = 0; i < EPB; i++) {
            if (dv[i] >= 0) {
                int b = dv[i] >> 8;
                int pos = base[b] + atomicAdd(&hist[b], 1);
                if (pos < BCAP)
                    bucket[(size_t)b * BCAP + pos] =
                        make_uint2((unsigned)sv[i], (unsigned)dv[i]);
            }
        }
        return;
    }

    // ---------------- layer-1 GEMM body (fp32 input, no BN fuse) ----------
    short* As = sm.g.As;
    short* Bs = sm.g.Bs;
    short* wl = sm.g.wl;
    int row0 = blockIdx.x * 64;

    for (int j = 0; j < 8; j++) {
        int idx = j * 256 + t;
        int nn = idx >> 4, cc = idx & 15;
        *(short8*)(Bs + nn * 128 + cc * 8) = *(const short8*)(Wt + nn * 128 + cc * 8);
    }
    if (t < 256) wl[t] = wsd[t];
    for (int j = 0; j < 8; j++) {
        int idx = j * 256 + t;
        int r = idx >> 5, k4 = idx & 31;
        int gr = row0 + r;
        float4 xv = make_float4(0.f, 0.f, 0.f, 0.f);
        if (gr < n) xv = *(const float4*)(Xf + (size_t)gr * CDIM + k4 * 4);
        short4v o;
        o.x = f2bf(xv.x); o.y = f2bf(xv.y); o.z = f2bf(xv.z); o.w = f2bf(xv.w);
        *(short4v*)(As + r * 128 + k4 * 4) = o;
    }
    __syncthreads();

    int w = t >> 6, lane = t & 63, q = lane >> 4, c = lane & 15;
    f32x4 zero = {0.f, 0.f, 0.f, 0.f};
    f32x4 acc[4][2];
    f32x4 acc_a = zero;               // alpha: col0=alpha_s, col1=alpha_d
    for (int i = 0; i < 4; i++) { acc[i][0] = zero; acc[i][1] = zero; }

    for (int ks = 0; ks < 4; ks++) {
        int k0 = ks * 32 + q * 8;
        short8 a0 = *(short8*)(As + (c) * 128 + k0);
        short8 a1 = *(short8*)(As + (16 + c) * 128 + k0);
        short8 a2 = *(short8*)(As + (32 + c) * 128 + k0);
        short8 a3 = *(short8*)(As + (48 + c) * 128 + k0);
        short8 b0 = *(short8*)(Bs + (w * 32 + c) * 128 + k0);
        short8 b1 = *(short8*)(Bs + (w * 32 + 16 + c) * 128 + k0);
        acc[0][0] = __builtin_amdgcn_mfma_f32_16x16x32_bf16(a0, b0, acc[0][0], 0, 0, 0);
        acc[1][0] = __builtin_amdgcn_mfma_f32_16x16x32_bf16(a1, b0, acc[1][0], 0, 0, 0);
        acc[2][0] = __builtin_amdgcn_mfma_f32_16x16x32_bf16(a2, b0, acc[2][0], 0, 0, 0);
        acc[3][0] = __builtin_amdgcn_mfma_f32_16x16x32_bf16(a3, b0, acc[3][0], 0, 0, 0);
        acc[0][1] = __builtin_amdgcn_mfma_f32_16x16x32_bf16(a0, b1, acc[0][1], 0, 0, 0);
        acc[1][1] = __builtin_amdgcn_mfma_f32_16x16x32_bf16(a1, b1, acc[1][1], 0, 0, 0);
        acc[2][1] = __builtin_amdgcn_mfma_f32_16x16x32_bf16(a2, b1, acc[2][1], 0, 0, 0);
        acc[3][1] = __builtin_amdgcn_mfma_f32_16x16x32_bf16(a3, b1, acc[3][1], 0, 0, 0);

        short8 ba;
        #pragma unroll
        for (int jj = 0; jj < 8; jj++) {
            short vs = wl[k0 + jj], vd = wl[128 + k0 + jj];
            ba[jj] = (c == 0) ? vs : ((c == 1) ? vd : (short)0);
        }
        short8 aw = (w == 0) ? a0 : ((w == 1) ? a1 : ((w == 2) ? a2 : a3));
        acc_a = __builtin_amdgcn_mfma_f32_16x16x32_bf16(aw, ba, acc_a, 0, 0, 0);
    }

    __syncthreads();                  // all As reads done before reuse

    short* Hs = As;
    #pragma unroll
    for (int mt = 0; mt < 4; mt++)
        #pragma unroll
        for (int nt = 0; nt < 2; nt++)
            #pragma unroll
            for (int r = 0; r < 4; r++)
                Hs[(mt * 16 + q * 4 + r) * 128 + w * 32 + nt * 16 + c] =
                    (short)__half_as_ushort(__float2half_rn(acc[mt][nt][r]));

    if (c < 2) {
        #pragma unroll
        for (int r = 0; r < 4; r++) {
            int row = row0 + w * 16 + q * 4 + r;
            if (row < n) {
                if (c == 0) alpha_s[row] = acc_a[r];
                else        alpha_d[row] = acc_a[r];
            }
        }
    }
    __syncthreads();

    for (int j = 0; j < 4; j++) {
        int idx = j * 256 + t;
        int r = idx >> 4, cc = idx & 15;
        int gr = row0 + r;
        if (gr < n)
            *(short8*)(Hh + (size_t)gr * 128 + cc * 8) = *(short8*)(Hs + r * 128 + cc * 8);
    }
}

// ---------------- per-bucket CSR build in LDS ------------------------------
__global__ __launch_bounds__(256) void k_fillB(
    const uint2* __restrict__ bucket, const int* __restrict__ bcur,
    int n, int NB, int* __restrict__ offs, int* __restrict__ csr)
{
    __shared__ int hist[256];
    __shared__ int scanb[256];
    __shared__ int cur[256];
    __shared__ int buf[BCAP + BRNG];
    int b = blockIdx.x, t = threadIdx.x;
    int node0 = b << 8;
    int nodesIn = min(BRNG, n - node0);
    int cnt = min(bcur[b], BCAP);
    const uint2* mybkt = bucket + (size_t)b * BCAP;

    int part = 0;
    for (int j = t; j < b; j += 256) part += min(bcur[j], BCAP);
    scanb[t] = part; __syncthreads();
    for (int s2 = 128; s2 > 0; s2 >>= 1) {
        if (t < s2) scanb[t] += scanb[t + s2];
        __syncthreads();
    }
    int base = scanb[0] + node0;
    __syncthreads();

    hist[t] = 0; __syncthreads();
    for (int e2 = t; e2 < cnt; e2 += 256)
        atomicAdd(&hist[mybkt[e2].y & 255], 1);
    __syncthreads();

    int v = hist[t] + ((t < nodesIn) ? 1 : 0);
    scanb[t] = v; __syncthreads();
    for (int d = 1; d < 256; d <<= 1) {
        int x2 = (t >= d) ? scanb[t - d] : 0;
        __syncthreads();
        scanb[t] += x2;
        __syncthreads();
    }
    int lo = scanb[t] - v;
    if (t < nodesIn) {
        offs[node0 + t] = base + lo;
        buf[lo] = node0 + t;          // self-loop occupies slot 0
        cur[t] = lo + 1;
    }
    __syncthreads();

    for (int e2 = t; e2 < cnt; e2 += 256) {
        uint2 ed = mybkt[e2];
        int pos = atomicAdd(&cur[ed.y & 255], 1);
        buf[pos] = (int)ed.x;
    }
    __syncthreads();

    int tot = cnt + nodesIn;
    for (int j2 = t; j2 < tot; j2 += 256) csr[base + j2] = buf[j2];
}

// ---------------- MFMA GEMM (layer 2): Hh = act(bn(G)) @ W, alpha fused ----
__global__ __launch_bounds__(256) void k_gemm_mfma(
    const unsigned* __restrict__ Xb, const short* __restrict__ Wt,
    const short* __restrict__ wsd,
    const float* __restrict__ bnsum, const float* __restrict__ gamma,
    const float* __restrict__ beta, float invn,
    short* __restrict__ Hh, float* __restrict__ alpha_s, float* __restrict__ alpha_d,
    int n)
{
    __shared__ short As[64 * 128];    // 16.4 KB (reused as H transpose buffer)
    __shared__ short Bs[128 * 128];   // 32.8 KB
    __shared__ short wl[256];         // ws (0..127), wd (128..255) bf16
    __shared__ float bnl[256];        // slot-summed BN stats
    int t = threadIdx.x;
    int row0 = blockIdx.x * 64;

    for (int j = 0; j < 8; j++) {
        int idx = j * 256 + t;
        int nn = idx >> 4, cc = idx & 15;
        *(short8*)(Bs + nn * 128 + cc * 8) = *(const short8*)(Wt + nn * 128 + cc * 8);
    }
    if (t < 256) wl[t] = wsd[t];
    // cooperative 32-slot reduction: thread t sums stat-index t
    {
        float s = 0.f;
        #pragma unroll
        for (int sl = 0; sl < NSLOT; sl++) s += bnsum[sl * 256 + t];
        bnl[t] = s;
    }
    __syncthreads();
    float4 sc4, sh4;
    {
        int cb = (t & 31) * 4;
        float mean, var;
        mean = bnl[cb + 0] * invn; var = fmaxf(bnl[128 + cb + 0] * invn - mean * mean, 0.f);
        sc4.x = gamma[cb + 0] * rsqrtf(var + BN_EPS_); sh4.x = beta[cb + 0] - mean * sc4.x;
        mean = bnl[cb + 1] * invn; var = fmaxf(bnl[128 + cb + 1] * invn - mean * mean, 0.f);
        sc4.y = gamma[cb + 1] * rsqrtf(var + BN_EPS_); sh4.y = beta[cb + 1] - mean * sc4.y;
        mean = bnl[cb + 2] * invn; var = fmaxf(bnl[128 + cb + 2] * invn - mean * mean, 0.f);
        sc4.z = gamma[cb + 2] * rsqrtf(var + BN_EPS_); sh4.z = beta[cb + 2] - mean * sc4.z;
        mean = bnl[cb + 3] * invn; var = fmaxf(bnl[128 + cb + 3] * invn - mean * mean, 0.f);
        sc4.w = gamma[cb + 3] * rsqrtf(var + BN_EPS_); sh4.w = beta[cb + 3] - mean * sc4.w;
    }
    for (int j = 0; j < 8; j++) {
        int idx = j * 256 + t;
        int r = idx >> 5, k4 = idx & 31;
        int gr = row0 + r;
        float4 xv = make_float4(0.f, 0.f, 0.f, 0.f);
        if (gr < n) {
            uint2 u = *(const uint2*)(Xb + (size_t)gr * 64 + k4 * 2);
            xv.x = bf_lo(u.x); xv.y = bf_hi(u.x);
            xv.z = bf_lo(u.y); xv.w = bf_hi(u.y);
        }
        xv.x = fmaxf(fmaf(xv.x, sc4.x, sh4.x), 0.f);
        xv.y = fmaxf(fmaf(xv.y, sc4.y, sh4.y), 0.f);
        xv.z = fmaxf(fmaf(xv.z, sc4.z, sh4.z), 0.f);
        xv.w = fmaxf(fmaf(xv.w, sc4.w, sh4.w), 0.f);
        short4v o;
        o.x = f2bf(xv.x); o.y = f2bf(xv.y); o.z = f2bf(xv.z); o.w = f2bf(xv.w);
        *(short4v*)(As + r * 128 + k4 * 4) = o;
    }
    __syncthreads();

    int w = t >> 6, lane = t & 63, q = lane >> 4, c = lane & 15;
    f32x4 zero = {0.f, 0.f, 0.f, 0.f};
    f32x4 acc[4][2];
    f32x4 acc_a = zero;
    for (int i = 0; i < 4; i++) { acc[i][0] = zero; acc[i][1] = zero; }

    for (int ks = 0; ks < 4; ks++) {
        int k0 = ks * 32 + q * 8;
        short8 a0 = *(short8*)(As + (c) * 128 + k0);
        short8 a1 = *(short8*)(As + (16 + c) * 128 + k0);
        short8 a2 = *(short8*)(As + (32 + c) * 128 + k0);
        short8 a3 = *(short8*)(As + (48 + c) * 128 + k0);
        short8 b0 = *(short8*)(Bs + (w * 32 + c) * 128 + k0);
        short8 b1 = *(short8*)(Bs + (w * 32 + 16 + c) * 128 + k0);
        acc[0][0] = __builtin_amdgcn_mfma_f32_16x16x32_bf16(a0, b0, acc[0][0], 0, 0, 0);
        acc[1][0] = __builtin_amdgcn_mfma_f32_16x16x32_bf16(a1, b0, acc[1][0], 0, 0, 0);
        acc[2][0] = __builtin_amdgcn_mfma_f32_16x16x32_bf16(a2, b0, acc[2][0], 0, 0, 0);
        acc[3][0] = __builtin_amdgcn_mfma_f32_16x16x32_bf16(a3, b0, acc[3][0], 0, 0, 0);
        acc[0][1] = __builtin_amdgcn_mfma_f32_16x16x32_bf16(a0, b1, acc[0][1], 0, 0, 0);
        acc[1][1] = __builtin_amdgcn_mfma_f32_16x16x32_bf16(a1, b1, acc[1][1], 0, 0, 0);
        acc[2][1] = __builtin_amdgcn_mfma_f32_16x16x32_bf16(a2, b1, acc[2][1], 0, 0, 0);
        acc[3][1] = __builtin_amdgcn_mfma_f32_16x16x32_bf16(a3, b1, acc[3][1], 0, 0, 0);

        short8 ba;
        #pragma unroll
        for (int jj = 0; jj < 8; jj++) {
            short vs = wl[k0 + jj], vd = wl[128 + k0 + jj];
            ba[jj] = (c == 0) ? vs : ((c == 1) ? vd : (short)0);
        }
        short8 aw = (w == 0) ? a0 : ((w == 1) ? a1 : ((w == 2) ? a2 : a3));
        acc_a = __builtin_amdgcn_mfma_f32_16x16x32_bf16(aw, ba, acc_a, 0, 0, 0);
    }

    __syncthreads();

    short* Hs = As;
    #pragma unroll
    for (int mt = 0; mt < 4; mt++)
        #pragma unroll
        for (int nt = 0; nt < 2; nt++)
            #pragma unroll
            for (int r = 0; r < 4; r++)
                Hs[(mt * 16 + q * 4 + r) * 128 + w * 32 + nt * 16 + c] =
                    (short)__half_as_ushort(__float2half_rn(acc[mt][nt][r]));

    if (c < 2) {
        #pragma unroll
        for (int r = 0; r < 4; r++) {
            int row = row0 + w * 16 + q * 4 + r;
            if (row < n) {
                if (c == 0) alpha_s[row] = acc_a[r];
                else        alpha_d[row] = acc_a[r];
            }
        }
    }
    __syncthreads();

    for (int j = 0; j < 4; j++) {
        int idx = j * 256 + t;
        int r = idx >> 4, cc = idx & 15;
        int gr = row0 + r;
        if (gr < n)
            *(short8*)(Hh + (size_t)gr * 128 + cc * 8) = *(short8*)(Hs + r * 128 + cc * 8);
    }
}

// ================= shared phase bodies (verified R20 code) =================

// ---- agg for node-group g (4 nodes, wave per node); no LDS, no syncs ------
static __device__ void agg_group(
    const unsigned* __restrict__ Hh, const int* __restrict__ offs,
    const int* __restrict__ csr, const float* __restrict__ alpha_s,
    const float* __restrict__ alpha_d, const float* __restrict__ bias,
    unsigned* __restrict__ Ob, int n, int g)
{
    int i = g * 4 + (threadIdx.x >> 6);
    int lane = threadIdx.x & 63;
    if (i >= n) return;
    int o0 = offs[i], o1 = offs[i + 1];
    float adi = alpha_d[i];

    float m = -1e30f;
    float se = 0.f;
    __half2 acc2 = __floats2half2_rn(0.f, 0.f);

    for (int c0 = o0; c0 < o1; c0 += 64) {
        int j = c0 + lane;
        int cnt = min(64, o1 - c0);
        int sj = (j < o1) ? csr[j] : 0;   // invalid lanes -> row 0 (w=0)

        unsigned ua[8], ub[8], uc[8];
        #pragma unroll
        for (int q = 0; q < 8; q++) {
            int s = __builtin_amdgcn_readlane(sj, q);
            ua[q] = Hh[(size_t)(unsigned)s * 64 + lane];
        }
        if (cnt > 8) {
            #pragma unroll
            for (int q = 0; q < 8; q++) {
                int s = __builtin_amdgcn_readlane(sj, 8 + q);
                ub[q] = Hh[(size_t)(unsigned)s * 64 + lane];
            }
        }
        if (cnt > 16) {
            #pragma unroll
            for (int q = 0; q < 8; q++) {
                int s = __builtin_amdgcn_readlane(sj, 16 + q);
                uc[q] = Hh[(size_t)(unsigned)s * 64 + lane];
            }
        }

        float a = (j < o1) ? lrelu(alpha_s[sj] + adi) : -1e30f;
        float cm = a;
        #pragma unroll
        for (int o = 32; o > 0; o >>= 1) cm = fmaxf(cm, __shfl_xor(cm, o));
        if (cm > m) {
            float r = __expf(m - cm);
            se *= r;
            acc2 = __hmul2(acc2, __float2half2_rn(r));
            m = cm;
        }
        float wl2 = (j < o1) ? __expf(a - m) : 0.f;
        se += wl2;
        int wli = (int)h22u(__float2half2_rn(wl2));

        for (int b = 0; b < cnt; b += 24) {
            #pragma unroll
            for (int q = 0; q < 8; q++) {
                int wq = __builtin_amdgcn_readlane(wli, b + q);
                acc2 = __hfma2(u2h2(ua[q]), u2h2((unsigned)wq), acc2);
            }
            if (b + 24 < cnt) {
                #pragma unroll
                for (int q = 0; q < 8; q++) {
                    int s = __builtin_amdgcn_readlane(sj, b + 24 + q);
                    ua[q] = Hh[(size_t)(unsigned)s * 64 + lane];
                }
            }
            if (b + 8 < cnt) {
                #pragma unroll
                for (int q = 0; q < 8; q++) {
                    int wq = __builtin_amdgcn_readlane(wli, b + 8 + q);
                    acc2 = __hfma2(u2h2(ub[q]), u2h2((unsigned)wq), acc2);
                }
                if (b + 32 < cnt) {
                    #pragma unroll
                    for (int q = 0; q < 8; q++) {
                        int s = __builtin_amdgcn_readlane(sj, b + 32 + q);
                        ub[q] = Hh[(size_t)(unsigned)s * 64 + lane];
                    }
                }
                if (b + 16 < cnt) {
                    #pragma unroll
                    for (int q = 0; q < 8; q++) {
                        int wq = __builtin_amdgcn_readlane(wli, b + 16 + q);
                        acc2 = __hfma2(u2h2(uc[q]), u2h2((unsigned)wq), acc2);
                    }
                    if (b + 40 < cnt) {
                        #pragma unroll
                        for (int q = 0; q < 8; q++) {
                            int s = __builtin_amdgcn_readlane(sj, b + 40 + q);
                            uc[q] = Hh[(size_t)(unsigned)s * 64 + lane];
                        }
                    }
                }
            }
        }
    }

    #pragma unroll
    for (int o = 32; o > 0; o >>= 1) se += __shfl_xor(se, o);
    float inv = 1.f / se;
    float2 af = __half22float2(acc2);
    float2 b2 = *(const float2*)(bias + lane * 2);
    float rx = fmaf(af.x, inv, b2.x);
    float ry = fmaf(af.y, inv, b2.y);
    unsigned pack = ((unsigned)(unsigned short)f2bf(ry) << 16) |
                    (unsigned)(unsigned short)f2bf(rx);
    Ob[(size_t)i * 64 + lane] = pack;
}

// ---- BN stats, grid-stride, 32-slot atomic output -------------------------
static __device__ void bnstats_gs(const unsigned* __restrict__ Hb, int n,
                                  float* __restrict__ sums, float (*red)[64][4])
{
    int w = threadIdx.x & 63;
    int g = threadIdx.x >> 6;
    float slo = 0.f, shi = 0.f, qlo = 0.f, qhi = 0.f;
    for (int r = blockIdx.x * 4 + g; r < n; r += gridDim.x * 4) {
        unsigned u = Hb[(size_t)r * 64 + w];
        float lo = bf_lo(u), hi = bf_hi(u);
        slo += lo; shi += hi; qlo += lo * lo; qhi += hi * hi;
    }
    red[g][w][0] = slo; red[g][w][1] = shi; red[g][w][2] = qlo; red[g][w][3] = qhi;
    __syncthreads();
    if (threadIdx.x < 64) {
        int w2 = threadIdx.x;
        float s0 = 0.f, s1 = 0.f, s2 = 0.f, s3 = 0.f;
        for (int gg = 0; gg < 4; gg++) {
            s0 += red[gg][w2][0]; s1 += red[gg][w2][1];
            s2 += red[gg][w2][2]; s3 += red[gg][w2][3];
        }
        float* bp = sums + (blockIdx.x & (NSLOT - 1)) * 256;
        atomicAdd(&bp[2 * w2], s0);
        atomicAdd(&bp[2 * w2 + 1], s1);
        atomicAdd(&bp[128 + 2 * w2], s2);
        atomicAdd(&bp[128 + 2 * w2 + 1], s3);
    }
}

// ---- classifier tile: out[tile*64 .. +63] = relu(bn(G)) @ Wc + bc ---------
static __device__ void cls_tile(
    const unsigned* __restrict__ G, const short* __restrict__ Wtc,
    const float* __restrict__ bc, const float* __restrict__ bnsum,
    const float* __restrict__ gamma, const float* __restrict__ beta, float invn,
    float* __restrict__ out, int n, int tile,
    short* As, short* Bs, float* bnl)
{
    int t = threadIdx.x;
    int row0 = tile * 64;
    __syncthreads();                 // guard LDS reuse across tiles/phases

    for (int j = 0; j < 3; j++) {
        int idx = j * 256 + t;       // 768 short8 = 6144 shorts
        *(short8*)(Bs + idx * 8) = *(const short8*)(Wtc + idx * 8);
    }
    {
        float s = 0.f;
        #pragma unroll
        for (int sl = 0; sl < NSLOT; sl++) s += bnsum[sl * 256 + t];
        bnl[t] = s;
    }
    __syncthreads();
    float4 sc4, sh4;
    {
        int cb = (t & 31) * 4;
        float mean, var;
        mean = bnl[cb + 0] * invn; var = fmaxf(bnl[128 + cb + 0] * invn - mean * mean, 0.f);
        sc4.x = gamma[cb + 0] * rsqrtf(var + BN_EPS_); sh4.x = beta[cb + 0] - mean * sc4.x;
        mean = bnl[cb + 1] * invn; var = fmaxf(bnl[128 + cb + 1] * invn - mean * mean, 0.f);
        sc4.y = gamma[cb + 1] * rsqrtf(var + BN_EPS_); sh4.y = beta[cb + 1] - mean * sc4.y;
        mean = bnl[cb + 2] * invn; var = fmaxf(bnl[128 + cb + 2] * invn - mean * mean, 0.f);
        sc4.z = gamma[cb + 2] * rsqrtf(var + BN_EPS_); sh4.z = beta[cb + 2] - mean * sc4.z;
        mean = bnl[cb + 3] * invn; var = fmaxf(bnl[128 + cb + 3] * invn - mean * mean, 0.f);
        sc4.w = gamma[cb + 3] * rsqrtf(var + BN_EPS_); sh4.w = beta[cb + 3] - mean * sc4.w;
    }
    for (int j = 0; j < 8; j++) {
        int idx = j * 256 + t;
        int r = idx >> 5, k4 = idx & 31;
        int gr = row0 + r;
        float4 xv = make_float4(0.f, 0.f, 0.f, 0.f);
        if (gr < n) {
            uint2 u = *(const uint2*)(G + (size_t)gr * 64 + k4 * 2);
            xv.x = bf_lo(u.x); xv.y = bf_hi(u.x);
            xv.z = bf_lo(u.y); xv.w = bf_hi(u.y);
        }
        xv.x = fmaxf(fmaf(xv.x, sc4.x, sh4.x), 0.f);
        xv.y = fmaxf(fmaf(xv.y, sc4.y, sh4.y), 0.f);
        xv.z = fmaxf(fmaf(xv.z, sc4.z, sh4.z), 0.f);
        xv.w = fmaxf(fmaf(xv.w, sc4.w, sh4.w), 0.f);
        short4v o;
        o.x = f2bf(xv.x); o.y = f2bf(xv.y); o.z = f2bf(xv.z); o.w = f2bf(xv.w);
        *(short4v*)(As + r * 128 + k4 * 4) = o;
    }
    __syncthreads();

    int w = t >> 6, lane = t & 63, q = lane >> 4, c = lane & 15;
    f32x4 zero = {0.f, 0.f, 0.f, 0.f};
    f32x4 acc[3] = {zero, zero, zero};
    for (int ks = 0; ks < 4; ks++) {
        int k0 = ks * 32 + q * 8;
        short8 a  = *(short8*)(As + (w * 16 + c) * 128 + k0);
        short8 b0 = *(short8*)(Bs + (c) * 128 + k0);
        short8 b1 = *(short8*)(Bs + (16 + c) * 128 + k0);
        short8 b2 = *(short8*)(Bs + (32 + c) * 128 + k0);
        acc[0] = __builtin_amdgcn_mfma_f32_16x16x32_bf16(a, b0, acc[0], 0, 0, 0);
        acc[1] = __builtin_amdgcn_mfma_f32_16x16x32_bf16(a, b1, acc[1], 0, 0, 0);
        acc[2] = __builtin_amdgcn_mfma_f32_16x16x32_bf16(a, b2, acc[2], 0, 0, 0);
    }
    float bc0 = bc[c], bc1 = bc[16 + c], bc2 = (c < 8) ? bc[32 + c] : 0.f;
    #pragma unroll
    for (int r = 0; r < 4; r++) {
        int row = row0 + w * 16 + q * 4 + r;
        if (row < n) {
            out[(size_t)row * NCLS_ + c]      = acc[0][r] + bc0;
            out[(size_t)row * NCLS_ + 16 + c] = acc[1][r] + bc1;
            if (c < 8) out[(size_t)row * NCLS_ + 32 + c] = acc[2][r] + bc2;
        }
    }
}

// ================= standalone kernels (R20 structure, capture-safe path) ===

__global__ __launch_bounds__(256) void k_agg(
    const unsigned* __restrict__ Hh, const int* __restrict__ offs,
    const int* __restrict__ csr, const float* __restrict__ alpha_s,
    const float* __restrict__ alpha_d, const float* __restrict__ bias,
    unsigned* __restrict__ Ob, int n)
{
    agg_group(Hh, offs, csr, alpha_s, alpha_d, bias, Ob, n, blockIdx.x);
}

__global__ __launch_bounds__(256) void k_bnstats(
    const unsigned* __restrict__ Hb, int n, float* __restrict__ sums)
{
    __shared__ float red[4][64][4];
    bnstats_gs(Hb, n, sums, red);
}

__global__ __launch_bounds__(256) void k_cls(
    const unsigned* __restrict__ G, const short* __restrict__ Wtc,
    const float* __restrict__ bc, const float* __restrict__ bnsum,
    const float* __restrict__ gamma, const float* __restrict__ beta, float invn,
    float* __restrict__ out, int n)
{
    __shared__ short As[64 * 128];
    __shared__ short Bs[48 * 128];
    __shared__ float bnl[256];
    cls_tile(G, Wtc, bc, bnsum, gamma, beta, invn, out, n, blockIdx.x, As, Bs, bnl);
}

// ================= cooperative fused kernels (non-capture path only) =======

// coop1: agg (grid-stride) -> grid.sync -> bnstats. LDS 4KB.
__global__ __launch_bounds__(256) void k_aggbn(
    const unsigned* __restrict__ Hh, const int* __restrict__ offs,
    const int* __restrict__ csr, const float* __restrict__ alpha_s,
    const float* __restrict__ alpha_d, const float* __restrict__ bias,
    unsigned* __restrict__ Ob, float* __restrict__ bnout, int n)
{
    __shared__ float red[4][64][4];
    int ng = (n + 3) >> 2;
    for (int g = blockIdx.x; g < ng; g += gridDim.x)
        agg_group(Hh, offs, csr, alpha_s, alpha_d, bias, Ob, n, g);
    __threadfence();
    cg::this_grid().sync();
    bnstats_gs(Ob, n, bnout, red);
}

// coop2: agg -> sync -> bnstats -> sync -> classifier. LDS ~29.7KB.
__global__ __launch_bounds__(256) void k_aggbncls(
    const unsigned* __restrict__ Hh, const int* __restrict__ offs,
    const int* __restrict__ csr, const float* __restrict__ alpha_s,
    const float* __restrict__ alpha_d, const float* __restrict__ bias,
    unsigned* __restrict__ Ob, float* __restrict__ bnout, int n,
    const short* __restrict__ Wtc, const float* __restrict__ bc,
    const float* __restrict__ gamma, const float* __restrict__ beta,
    float invn, float* __restrict__ out)
{
    __shared__ union {
        float red[4][64][4];
        struct { short As[64 * 128]; short Bs[48 * 128]; float bnl[256]; } c;
    } sm;
    int ng = (n + 3) >> 2;
    for (int g = blockIdx.x; g < ng; g += gridDim.x)
        agg_group(Hh, offs, csr, alpha_s, alpha_d, bias, Ob, n, g);
    __threadfence();
    cg::this_grid().sync();
    bnstats_gs(Ob, n, bnout, sm.red);
    __threadfence();
    cg::this_grid().sync();
    int gemmN = (n + 63) >> 6;
    for (int tile = blockIdx.x; tile < gemmN; tile += gridDim.x)
        cls_tile(Ob, Wtc, bc, bnout, gamma, beta, invn, out, n, tile,
                 sm.c.As, sm.c.Bs, sm.c.bnl);
}

// ---------------- launch ---------------------------------------------------
extern "C" void kernel_launch(void* const* d_in, const int* in_sizes, int n_in,
                              void* d_out, int out_size, void* d_ws, size_t ws_size,
                              hipStream_t stream)
{
    const float* x   = (const float*)d_in[0];
    const int*   ei  = (const int*)d_in[1];
    const float* W1  = (const float*)d_in[2];
    const float* as1 = (const float*)d_in[3];
    const float* ad1 = (const float*)d_in[4];
    const float* b1  = (const float*)d_in[5];
    const float* g1  = (const float*)d_in[6];
    const float* be1 = (const float*)d_in[7];
    const float* W2  = (const float*)d_in[8];
    const float* as2 = (const float*)d_in[9];
    const float* ad2 = (const float*)d_in[10];
    const float* b2  = (const float*)d_in[11];
    const float* g2  = (const float*)d_in[12];
    const float* be2 = (const float*)d_in[13];
    const float* Wc  = (const float*)d_in[14];
    const float* bc  = (const float*)d_in[15];
    float* out = (float*)d_out;

    int n = in_sizes[0] / CDIM;     // 100000
    int E = in_sizes[1] / 2;        // 1600000
    const int* src = ei;
    const int* dst = ei + E;
    float invn = 1.f / (float)n;
    int NB = (n + BRNG - 1) / BRNG; // 391

    // workspace layout (64B-aligned chunks)
    char* p = (char*)d_ws;
    auto alloc = [&p](size_t bytes) { char* q = p; p += (bytes + 63) & ~(size_t)63; return q; };
    short*    Hh      = (short*)alloc((size_t)n * CDIM * sizeof(short));
    unsigned* bufB    = (unsigned*)alloc((size_t)n * 64 * sizeof(unsigned));
    float*    alpha_s = (float*)alloc((size_t)n * sizeof(float));
    float*    alpha_d = (float*)alloc((size_t)n * sizeof(float));
    float*    bnsum   = (float*)alloc(2 * NSLOT * 256 * sizeof(float)); // 64 KB
    short*    Wt1     = (short*)alloc(128 * 128 * sizeof(short));
    short*    Wt2     = (short*)alloc(128 * 128 * sizeof(short));
    short*    Wtc     = (short*)alloc(48 * 128 * sizeof(short));
    short*    wsd1    = (short*)alloc(256 * sizeof(short));
    short*    wsd2    = (short*)alloc(256 * sizeof(short));
    int*      bcurs   = (int*)alloc((size_t)NB * sizeof(int));
    int*      offs    = (int*)alloc((size_t)(n + 1) * sizeof(int));
    uint2*    bucket  = (uint2*)alloc((size_t)NB * BCAP * sizeof(uint2));
    int*      csr     = (int*)alloc((size_t)(E + n) * sizeof(int));

    // ---- capture gate: cooperative launch is NOT graph-capture-safe. ----
    hipStreamCaptureStatus cst = hipStreamCaptureStatusNone;
    bool gate_ok = (hipStreamIsCapturing(stream, &cst) == hipSuccess);
    bool try_coop = gate_ok && (cst == hipStreamCaptureStatusNone);

    k_setup<<<dim3(64), dim3(256), 0, stream>>>(bcurs, bnsum, NB, n, E, offs,
                                                W1, W2, Wc, as1, ad1, as2, ad2,
                                                Wt1, Wt2, Wtc, wsd1, wsd2);

    int gemmN = (n + 63) / 64;            // 1563
    int binN  = (E + 4095) / 4096;        // 391
    k_pre<<<dim3(gemmN + binN), dim3(256), 0, stream>>>(
        x, Wt1, wsd1, Hh, alpha_s, alpha_d, n, gemmN,
        src, dst, E, bcurs, bucket, NB);

    k_fillB<<<dim3(NB), dim3(256), 0, stream>>>(bucket, bcurs, n, NB, offs, csr);

    dim3 ggrid(gemmN);
    dim3 wgrid((n + 3) / 4);
    int ngroups = (n + 3) / 4;
    const unsigned* HhC = (const unsigned*)Hh;

    // ---- layer 1: agg + bnstats ----
    bool done1 = false;
    if (try_coop) {
        int occ1 = 0;
        if (hipOccupancyMaxActiveBlocksPerMultiprocessor(
                &occ1, (const void*)k_aggbn, 256, 0) == hipSuccess && occ1 > 0) {
            int grid1 = occ1 * 256; if (grid1 > ngroups) grid1 = ngroups;
            float* bn1 = bnsum;
            void* a1[] = {(void*)&HhC, (void*)&offs, (void*)&csr, (void*)&alpha_s,
                          (void*)&alpha_d, (void*)&b1, (void*)&bufB, (void*)&bn1,
                          (void*)&n};
            done1 = hipLaunchCooperativeKernel((const void*)k_aggbn, dim3(grid1),
                                               dim3(256), a1, 0, stream) == hipSuccess;
        }
    }
    if (!done1) {
        k_agg<<<wgrid, 256, 0, stream>>>(HhC, offs, csr, alpha_s, alpha_d, b1, bufB, n);
        k_bnstats<<<dim3(2048), dim3(256), 0, stream>>>(bufB, n, bnsum);
    }

    // ---- layer 2 GEMM (BN1+relu folded from 32-slot sums) ----
    k_gemm_mfma<<<ggrid, 256, 0, stream>>>(bufB, Wt2, wsd2, bnsum, g1, be1,
                                           invn, Hh, alpha_s, alpha_d, n);

    // ---- layer 2: agg + bnstats + classifier ----
    bool done2 = false;
    if (try_coop) {
        int occ2 = 0;
        if (hipOccupancyMaxActiveBlocksPerMultiprocessor(
                &occ2, (const void*)k_aggbncls, 256, 0) == hipSuccess && occ2 > 0) {
            int grid2 = occ2 * 256; if (grid2 > ngroups) grid2 = ngroups;
            float* bn2 = bnsum + NSLOT * 256;
            void* a2[] = {(void*)&HhC, (void*)&offs, (void*)&csr, (void*)&alpha_s,
                          (void*)&alpha_d, (void*)&b2, (void*)&bufB, (void*)&bn2,
                          (void*)&n, (void*)&Wtc, (void*)&bc, (void*)&g2, (void*)&be2,
                          (void*)&invn, (void*)&out};
            done2 = hipLaunchCooperativeKernel((const void*)k_aggbncls, dim3(grid2),
                                               dim3(256), a2, 0, stream) == hipSuccess;
        }
    }
    if (!done2) {
        k_agg<<<wgrid, 256, 0, stream>>>(HhC, offs, csr, alpha_s, alpha_d, b2, bufB, n);
        k_bnstats<<<dim3(2048), dim3(256), 0, stream>>>(bufB, n, bnsum + NSLOT * 256);
        k_cls<<<ggrid, 256, 0, stream>>>(bufB, Wtc, bc, bnsum + NSLOT * 256, g2, be2,
                                         invn, out, n);
    }
}